// Round 17
// baseline (652.960 us; speedup 1.0000x reference)
//
#include <hip/hip_runtime.h>

// ---------------------------------------------------------------------------
// DecoderBlock on MI355X (gfx950).  B=2, L=2048, D=2048, H=16, DH=128, FF=8192
// Round 17: R16 (best: 629.4us) + T13 defer-max in attention softmax:
// skip m-update/alpha-rescale when tile_max <= m_row + 8 (exact math, P
// bounded by e^8).  Everything else byte-identical to passing R16.
// ---------------------------------------------------------------------------

typedef __bf16 bf16;
typedef __bf16 bf16x8 __attribute__((ext_vector_type(8)));
typedef float  f32x4  __attribute__((ext_vector_type(4)));

__device__ __forceinline__ void gload16(const void* g, void* l) {
  __builtin_amdgcn_global_load_lds((const __attribute__((address_space(1))) void*)g,
                                   (__attribute__((address_space(3))) void*)l,
                                   16, 0, 0);
}

#define CBAR asm volatile("" ::: "memory")
#define WAITV(N) asm volatile("s_waitcnt vmcnt(" #N ")" ::: "memory")
#define LGKM0 asm volatile("s_waitcnt lgkmcnt(0)" ::: "memory")
#define BARR { CBAR; __builtin_amdgcn_s_barrier(); CBAR; }

// ------------------------------ RMSNorm (f32 -> bf16, linear) --------------
__global__ __launch_bounds__(256) void rmsnorm_to_bf16(
    const float* __restrict__ x, const float* __restrict__ w, bf16* __restrict__ out)
{
  const int D = 2048;
  const int row = blockIdx.x;
  const int tid = threadIdx.x;
  const float* xr = x + (size_t)row * D;
  float4 a = ((const float4*)xr)[tid * 2];
  float4 c = ((const float4*)xr)[tid * 2 + 1];
  float ss = a.x*a.x + a.y*a.y + a.z*a.z + a.w*a.w
           + c.x*c.x + c.y*c.y + c.z*c.z + c.w*c.w;
  #pragma unroll
  for (int m = 1; m < 64; m <<= 1) ss += __shfl_xor(ss, m, 64);
  __shared__ float red[4];
  if ((tid & 63) == 0) red[tid >> 6] = ss;
  __syncthreads();
  float tot = red[0] + red[1] + red[2] + red[3];
  float rms = rsqrtf(tot * (1.0f / D) + 1.1920929e-7f);
  const float* wr = w + tid * 8;
  float vals[8] = {a.x, a.y, a.z, a.w, c.x, c.y, c.z, c.w};
  bf16x8 o;
  #pragma unroll
  for (int j = 0; j < 8; ++j) o[j] = (bf16)(vals[j] * rms * wr[j]);
  *(bf16x8*)(out + (size_t)row * D + tid * 8) = o;
}

// --------------------- transpose + convert f32[R][C] -> bf16[C][R] ---------
__global__ __launch_bounds__(256) void transpose_to_bf16(
    const float* __restrict__ in, bf16* __restrict__ out, int R, int C)
{
  __shared__ float tile[32][33];
  const int tx = threadIdx.x, ty = threadIdx.y;      // 32 x 8
  const int c0 = blockIdx.x * 32, r0 = blockIdx.y * 32;
  #pragma unroll
  for (int i = 0; i < 4; ++i)
    tile[ty + i * 8][tx] = in[(size_t)(r0 + ty + i * 8) * C + c0 + tx];
  __syncthreads();
  #pragma unroll
  for (int i = 0; i < 4; ++i)
    out[(size_t)(c0 + ty + i * 8) * R + r0 + tx] = (bf16)tile[tx][ty + i * 8];
}

// ----- fused 4x (2048x2048) transpose: z selects {wq,wk,wv,wo} -------------
__global__ __launch_bounds__(256) void transpose4_to_bf16(
    const float* __restrict__ w0, const float* __restrict__ w1,
    const float* __restrict__ w2, const float* __restrict__ w3,
    bf16* __restrict__ o0, bf16* __restrict__ o1,
    bf16* __restrict__ o2, bf16* __restrict__ o3)
{
  const int R = 2048, C = 2048;
  __shared__ float tile[32][33];
  const int tx = threadIdx.x, ty = threadIdx.y;      // 32 x 8
  const int c0 = blockIdx.x * 32, r0 = blockIdx.y * 32;
  const int z = blockIdx.z;
  const float* in = (z == 0) ? w0 : (z == 1) ? w1 : (z == 2) ? w2 : w3;
  bf16* out = (z == 0) ? o0 : (z == 1) ? o1 : (z == 2) ? o2 : o3;
  #pragma unroll
  for (int i = 0; i < 4; ++i)
    tile[ty + i * 8][tx] = in[(size_t)(r0 + ty + i * 8) * C + c0 + tx];
  __syncthreads();
  #pragma unroll
  for (int i = 0; i < 4; ++i)
    out[(size_t)(c0 + ty + i * 8) * R + r0 + tx] = (bf16)tile[tx][ty + i * 8];
}

// --------------- V[b*L+key][h*128+dh] -> VT[(bh*128+dh)][key'] (bf16) ------
__global__ __launch_bounds__(256) void v_transpose(
    const bf16* __restrict__ v, bf16* __restrict__ vt)
{
  const int L = 2048, DM = 2048;
  __shared__ bf16 tile[32][33];
  const int tx = threadIdx.x, ty = threadIdx.y;      // 32 x 8
  const int k0 = blockIdx.x * 32;
  const int d0 = blockIdx.y * 32;
  const int bh = blockIdx.z;
  const int b = bh >> 4, h = bh & 15;
  #pragma unroll
  for (int i = 0; i < 4; ++i)
    tile[ty + i * 8][tx] = v[(size_t)(b * L + k0 + ty + i * 8) * DM + h * 128 + d0 + tx];
  __syncthreads();
  #pragma unroll
  for (int i = 0; i < 4; ++i) {
    const int d = d0 + ty + i * 8;
    const int key = k0 + tx;
    const int keysw = (key & ~63) | (((((key >> 3) & 7) ^ (d & 7)) << 3)) | (key & 7);
    vt[(size_t)(bh * 128 + d) * L + keysw] = tile[tx][ty + i * 8];
  }
}

// ------------- 256x256 4-phase GEMM, 7-unit deep prefetch (BK=64) ----------
// R11 schedule + hoisted addresses.  EPI: 2 = silu bf16
template<int EPI>
__global__ __launch_bounds__(512, 1) void gemm256(
    const bf16* __restrict__ A, const bf16* __restrict__ Bt,
    void* Cout, const float* __restrict__ resid, int M, int N, int K)
{
  __shared__ bf16 sA[2][2][128 * 64];   // 64 KB ; buf stride 32768B, rh 16384B
  __shared__ bf16 sB[2][2][128 * 64];   // 64 KB

  const int tid = threadIdx.x, lane = tid & 63, w = tid >> 6;
  const int wm = w >> 2, wn = w & 3;
  const int lo = lane & 15, hi = lane >> 4;
  const int lo7 = lo & 7;

  const int nbn = N >> 8;
  const int nwg = gridDim.x;
  int swz = blockIdx.x;
  if ((nwg & 7) == 0) { const int cpx = nwg >> 3; swz = (swz & 7) * cpx + (swz >> 3); }
  const int bm = swz / nbn, bn = swz % nbn;

  const int r0 = tid >> 3,         s0 = (tid & 7) ^ (r0 & 7);
  const int r1 = (512 + tid) >> 3, s1 = ((512 + tid) & 7) ^ (r1 & 7);
  const bf16* Ab = A  + (size_t)(bm * 256) * K;
  const bf16* Bb = Bt + (size_t)(bn * 256) * K;
  const size_t o0 = (size_t)r0 * K + s0 * 8;
  const size_t o1 = (size_t)r1 * K + s1 * 8;
  const int dst0 = (w * 64) * 8, dst1 = (512 + w * 64) * 8;
  const size_t rhK = (size_t)128 * K;

  unsigned offA[2][4], offB[2][2];
  #pragma unroll
  for (int ks = 0; ks < 2; ++ks) {
    #pragma unroll
    for (int m = 0; m < 4; ++m)
      offA[ks][m] = (unsigned)((((wm * 64 + m * 16 + lo) * 64) + (((ks * 4 + hi) ^ lo7) << 3)) * 2);
    #pragma unroll
    for (int nj = 0; nj < 2; ++nj)
      offB[ks][nj] = (unsigned)((((wn * 32 + nj * 16 + lo) * 64) + (((ks * 4 + hi) ^ lo7) << 3)) * 2);
  }

  const bf16* pA1_0 = Ab + rhK + 64 + o0;  const bf16* pA1_1 = Ab + rhK + 64 + o1;
  const bf16* pA0_0 = Ab + 128 + o0;       const bf16* pA0_1 = Ab + 128 + o1;
  const bf16* pB0_0 = Bb + 128 + o0;       const bf16* pB0_1 = Bb + 128 + o1;
  const bf16* pB1_0 = Bb + rhK + 128 + o0; const bf16* pB1_1 = Bb + rhK + 128 + o1;

  bf16x8 a0[2][4], a1[2][4], b0[2][2], b1[2][2];
  f32x4 acc[8][4] = {};
  const int NT = K >> 6;

  auto loadA = [&](bf16x8 (&d)[2][4], int b, int rh) {
    const char* base = (const char*)(&sA[0][0][0]) + b * 32768 + rh * 16384;
    #pragma unroll
    for (int ks = 0; ks < 2; ++ks)
      #pragma unroll
      for (int m = 0; m < 4; ++m)
        d[ks][m] = *(const bf16x8*)(base + offA[ks][m]);
  };
  auto loadB = [&](bf16x8 (&d)[2][2], int b, int rh) {
    const char* base = (const char*)(&sB[0][0][0]) + b * 32768 + rh * 16384;
    #pragma unroll
    for (int ks = 0; ks < 2; ++ks)
      #pragma unroll
      for (int nj = 0; nj < 2; ++nj)
        d[ks][nj] = *(const bf16x8*)(base + offB[ks][nj]);
  };
  auto mfma16 = [&](bf16x8 (&a)[2][4], bf16x8 (&bf)[2][2], int mb, int nb2) {
    __builtin_amdgcn_s_setprio(1);
    #pragma unroll
    for (int ks = 0; ks < 2; ++ks)
      #pragma unroll
      for (int m = 0; m < 4; ++m)
        #pragma unroll
        for (int nj = 0; nj < 2; ++nj)
          acc[mb + m][nb2 + nj] = __builtin_amdgcn_mfma_f32_16x16x32_bf16(
              a[ks][m], bf[ks][nj], acc[mb + m][nb2 + nj], 0, 0, 0);
    __builtin_amdgcn_s_setprio(0);
  };

  {
    gload16(Ab + o0, &sA[0][0][dst0]);        gload16(Ab + o1, &sA[0][0][dst1]);
    gload16(Bb + o0, &sB[0][0][dst0]);        gload16(Bb + o1, &sB[0][0][dst1]);
    gload16(Bb + rhK + o0, &sB[0][1][dst0]);  gload16(Bb + rhK + o1, &sB[0][1][dst1]);
    gload16(Ab + rhK + o0, &sA[0][1][dst0]);  gload16(Ab + rhK + o1, &sA[0][1][dst1]);
    gload16(Ab + 64 + o0, &sA[1][0][dst0]);   gload16(Ab + 64 + o1, &sA[1][0][dst1]);
    gload16(Bb + 64 + o0, &sB[1][0][dst0]);   gload16(Bb + 64 + o1, &sB[1][0][dst1]);
    gload16(Bb + rhK + 64 + o0, &sB[1][1][dst0]); gload16(Bb + rhK + 64 + o1, &sB[1][1][dst1]);
  }
  WAITV(6);
  BARR;

  for (int t = 0; t < NT; ++t) {
    const int buf = t & 1, nb = buf ^ 1;
    const int u = 4 * t;
    loadA(a0, buf, 0);
    loadB(b0, buf, 0);
    if (u + 7 < 4 * NT) { gload16(pA1_0, &sA[nb][1][dst0]); gload16(pA1_1, &sA[nb][1][dst1]); }
    BARR; LGKM0;
    mfma16(a0, b0, 0, 0);
    BARR;
    loadB(b1, buf, 1);
    if (u + 8 < 4 * NT) { gload16(pA0_0, &sA[buf][0][dst0]); gload16(pA0_1, &sA[buf][0][dst1]); }
    BARR; LGKM0;
    mfma16(a0, b1, 0, 2);
    BARR;
    loadA(a1, buf, 1);
    if (u + 9 < 4 * NT) { gload16(pB0_0, &sB[buf][0][dst0]); gload16(pB0_1, &sB[buf][0][dst1]); }
    BARR; LGKM0;
    mfma16(a1, b1, 4, 2);
    BARR;
    if (u + 10 < 4 * NT) { gload16(pB1_0, &sB[buf][1][dst0]); gload16(pB1_1, &sB[buf][1][dst1]); }
    mfma16(a1, b0, 4, 0);
    if (t < NT - 2) { WAITV(6); } else if (t == NT - 2) { WAITV(0); }
    BARR;
    pA1_0 += 64; pA1_1 += 64; pA0_0 += 64; pA0_1 += 64;
    pB0_0 += 64; pB0_1 += 64; pB1_0 += 64; pB1_1 += 64;
  }

  #pragma unroll
  for (int mi = 0; mi < 8; ++mi) {
    #pragma unroll
    for (int j = 0; j < 4; ++j) {
      const size_t row = (size_t)(bm * 256 + (mi >> 2) * 128 + wm * 64 + (mi & 3) * 16 + hi * 4 + j);
      #pragma unroll
      for (int ni = 0; ni < 4; ++ni) {
        const int col = bn * 256 + (ni >> 1) * 128 + wn * 32 + (ni & 1) * 16 + lo;
        const float v = acc[mi][ni][j];
        if constexpr (EPI == 2) {
          ((bf16*)Cout)[row * (size_t)N + col] = (bf16)(v / (1.0f + __expf(-v)));
        } else {
          ((bf16*)Cout)[(size_t)(col >> 11) * 8388608 + row * 2048 + (col & 2047)] = (bf16)v;
        }
      }
    }
  }
}

// ------------- 128x256 2-phase GEMM, 5-unit deep prefetch (BK=64) ----------
// R11 schedule + hoisted addresses.  EPI: 1 = f32 + resid; 3 = q/k/v slabs
template<int EPI>
__global__ __launch_bounds__(512, 1) void gemm128(
    const bf16* __restrict__ A, const bf16* __restrict__ Bt,
    void* Cout, const float* __restrict__ resid, int M, int N, int K)
{
  __shared__ bf16 sA[2][128 * 64];      // 32 KB ; buf stride 16384B
  __shared__ bf16 sB[2][2][128 * 64];   // 64 KB ; buf stride 32768B, nh 16384B

  const int tid = threadIdx.x, lane = tid & 63, w = tid >> 6;
  const int wm = w >> 2, wn = w & 3;
  const int lo = lane & 15, hi = lane >> 4;
  const int lo7 = lo & 7;

  const int nbn = N >> 8;
  const int nwg = gridDim.x;
  int swz = blockIdx.x;
  if ((nwg & 7) == 0) { const int cpx = nwg >> 3; swz = (swz & 7) * cpx + (swz >> 3); }
  const int bm = swz / nbn, bn = swz % nbn;

  const int r0 = tid >> 3,         s0 = (tid & 7) ^ (r0 & 7);
  const int r1 = (512 + tid) >> 3, s1 = ((512 + tid) & 7) ^ (r1 & 7);
  const bf16* Ab = A  + (size_t)(bm * 128) * K;
  const bf16* Bb = Bt + (size_t)(bn * 256) * K;
  const size_t o0 = (size_t)r0 * K + s0 * 8;
  const size_t o1 = (size_t)r1 * K + s1 * 8;
  const int dst0 = (w * 64) * 8, dst1 = (512 + w * 64) * 8;
  const size_t nhK = (size_t)128 * K;

  unsigned offA[2][4], offB[2][2];
  #pragma unroll
  for (int ks = 0; ks < 2; ++ks) {
    #pragma unroll
    for (int m = 0; m < 4; ++m)
      offA[ks][m] = (unsigned)((((wm * 64 + m * 16 + lo) * 64) + (((ks * 4 + hi) ^ lo7) << 3)) * 2);
    #pragma unroll
    for (int nj = 0; nj < 2; ++nj)
      offB[ks][nj] = (unsigned)((((wn * 32 + nj * 16 + lo) * 64) + (((ks * 4 + hi) ^ lo7) << 3)) * 2);
  }

  const bf16* pB1_0 = Bb + nhK + 64 + o0;  const bf16* pB1_1 = Bb + nhK + 64 + o1;
  const bf16* pA_0  = Ab + 128 + o0;       const bf16* pA_1  = Ab + 128 + o1;
  const bf16* pB0_0 = Bb + 128 + o0;       const bf16* pB0_1 = Bb + 128 + o1;

  bf16x8 afA[2][4], b0[2][2], b1[2][2];
  f32x4 acc[4][4] = {};
  const int NT = K >> 6;

  auto loadA = [&](int b) {
    const char* base = (const char*)(&sA[0][0]) + b * 16384;
    #pragma unroll
    for (int ks = 0; ks < 2; ++ks)
      #pragma unroll
      for (int m = 0; m < 4; ++m)
        afA[ks][m] = *(const bf16x8*)(base + offA[ks][m]);
  };
  auto loadB = [&](bf16x8 (&d)[2][2], int b, int nh) {
    const char* base = (const char*)(&sB[0][0][0]) + b * 32768 + nh * 16384;
    #pragma unroll
    for (int ks = 0; ks < 2; ++ks)
      #pragma unroll
      for (int nj = 0; nj < 2; ++nj)
        d[ks][nj] = *(const bf16x8*)(base + offB[ks][nj]);
  };
  auto mfma16 = [&](bf16x8 (&bf)[2][2], int nb2) {
    __builtin_amdgcn_s_setprio(1);
    #pragma unroll
    for (int ks = 0; ks < 2; ++ks)
      #pragma unroll
      for (int m = 0; m < 4; ++m)
        #pragma unroll
        for (int nj = 0; nj < 2; ++nj)
          acc[m][nb2 + nj] = __builtin_amdgcn_mfma_f32_16x16x32_bf16(
              afA[ks][m], bf[ks][nj], acc[m][nb2 + nj], 0, 0, 0);
    __builtin_amdgcn_s_setprio(0);
  };

  {
    gload16(Ab + o0, &sA[0][dst0]);           gload16(Ab + o1, &sA[0][dst1]);
    gload16(Bb + o0, &sB[0][0][dst0]);        gload16(Bb + o1, &sB[0][0][dst1]);
    gload16(Bb + nhK + o0, &sB[0][1][dst0]);  gload16(Bb + nhK + o1, &sB[0][1][dst1]);
    gload16(Ab + 64 + o0, &sA[1][dst0]);      gload16(Ab + 64 + o1, &sA[1][dst1]);
    gload16(Bb + 64 + o0, &sB[1][0][dst0]);   gload16(Bb + 64 + o1, &sB[1][0][dst1]);
  }
  WAITV(4);
  BARR;

  for (int t = 0; t < NT; ++t) {
    const int buf = t & 1, nb = buf ^ 1;
    const int u = 3 * t;
    loadA(buf);
    loadB(b0, buf, 0);
    if (u + 5 < 3 * NT) { gload16(pB1_0, &sB[nb][1][dst0]); gload16(pB1_1, &sB[nb][1][dst1]); }
    BARR; LGKM0;
    mfma16(b0, 0);
    BARR;
    loadB(b1, buf, 1);
    if (u + 6 < 3 * NT) { gload16(pA_0, &sA[buf][dst0]); gload16(pA_1, &sA[buf][dst1]); }
    if (u + 7 < 3 * NT) { gload16(pB0_0, &sB[buf][0][dst0]); gload16(pB0_1, &sB[buf][0][dst1]); }
    BARR; LGKM0;
    mfma16(b1, 2);
    if (t < NT - 2) { WAITV(4); } else if (t == NT - 2) { WAITV(0); }
    BARR;
    pB1_0 += 64; pB1_1 += 64; pA_0 += 64; pA_1 += 64; pB0_0 += 64; pB0_1 += 64;
  }

  #pragma unroll
  for (int mi = 0; mi < 4; ++mi) {
    #pragma unroll
    for (int j = 0; j < 4; ++j) {
      const size_t row = (size_t)(bm * 128 + wm * 64 + mi * 16 + hi * 4 + j);
      #pragma unroll
      for (int ni = 0; ni < 4; ++ni) {
        const int col = bn * 256 + (ni >> 1) * 128 + wn * 32 + (ni & 1) * 16 + lo;
        const float v = acc[mi][ni][j];
        if constexpr (EPI == 1) {
          const size_t ro = row * (size_t)N;
          ((float*)Cout)[ro + col] = v + resid[ro + col];
        } else {
          ((bf16*)Cout)[(size_t)(col >> 11) * 8388608 + row * 2048 + (col & 2047)] = (bf16)v;
        }
      }
    }
  }
}

// ------------------- RoPE: q in-place; k -> kswz with granule swizzle ------
__global__ __launch_bounds__(256) void rope_qk(
    bf16* q, const bf16* __restrict__ k, bf16* __restrict__ kswz,
    const float* __restrict__ cs, const float* __restrict__ sn)
{
  const int L = 2048, DM = 2048;
  const int idx = blockIdx.x * 256 + threadIdx.x;
  const int m = idx >> 7;
  const int rem = idx & 127;
  const int h = rem >> 3, t8 = rem & 7;
  const int pos = m & (L - 1);
  const int d0 = t8 * 8;
  const float* cb = cs + (size_t)pos * 128 + d0;
  const float* sb = sn + (size_t)pos * 128 + d0;
  float4 c1a = *(const float4*)(cb);      float4 c1b = *(const float4*)(cb + 4);
  float4 c2a = *(const float4*)(cb + 64); float4 c2b = *(const float4*)(cb + 68);
  float4 s1a = *(const float4*)(sb);      float4 s1b = *(const float4*)(sb + 4);
  float4 s2a = *(const float4*)(sb + 64); float4 s2b = *(const float4*)(sb + 68);
  float c1[8] = {c1a.x,c1a.y,c1a.z,c1a.w,c1b.x,c1b.y,c1b.z,c1b.w};
  float c2[8] = {c2a.x,c2a.y,c2a.z,c2a.w,c2b.x,c2b.y,c2b.z,c2b.w};
  float s1[8] = {s1a.x,s1a.y,s1a.z,s1a.w,s1b.x,s1b.y,s1b.z,s1b.w};
  float s2[8] = {s2a.x,s2a.y,s2a.z,s2a.w,s2b.x,s2b.y,s2b.z,s2b.w};
  const size_t base = (size_t)m * DM + h * 128 + d0;

  {
    bf16x8 x1 = *(bf16x8*)(q + base);
    bf16x8 x2 = *(bf16x8*)(q + base + 64);
    bf16x8 o1, o2;
    #pragma unroll
    for (int j = 0; j < 8; ++j) {
      const float a = (float)x1[j], b = (float)x2[j];
      o1[j] = (bf16)(a * c1[j] - b * s1[j]);
      o2[j] = (bf16)(b * c2[j] + a * s2[j]);
    }
    *(bf16x8*)(q + base) = o1;
    *(bf16x8*)(q + base + 64) = o2;
  }
  {
    bf16x8 x1 = *(const bf16x8*)(k + base);
    bf16x8 x2 = *(const bf16x8*)(k + base + 64);
    bf16x8 o1, o2;
    #pragma unroll
    for (int j = 0; j < 8; ++j) {
      const float a = (float)x1[j], b = (float)x2[j];
      o1[j] = (bf16)(a * c1[j] - b * s1[j]);
      o2[j] = (bf16)(b * c2[j] + a * s2[j]);
    }
    const int s = pos & 15;
    const int p1 = t8 ^ s;
    const int p2 = (8 + t8) ^ s;
    bf16* kr = kswz + (size_t)m * DM + h * 128;
    *(bf16x8*)(kr + p1 * 8) = o1;
    *(bf16x8*)(kr + p2 * 8) = o2;
  }
}

// ------------------------------ Flash attention (R13 + T13 defer-max) ------
__global__ __launch_bounds__(256, 2) void attn_fwd(
    const bf16* __restrict__ Q, const bf16* __restrict__ Kswz,
    const bf16* __restrict__ VT, const int* __restrict__ mask,
    bf16* __restrict__ O)
{
  const int L = 2048, DM = 2048;
  __shared__ bf16 Kt[2][64 * 128];
  __shared__ bf16 Vt[2][128 * 64];
  __shared__ bf16 Plds[4][16 * 64];

  const int tid = threadIdx.x, lane = tid & 63, w = tid >> 6;
  const int lo = lane & 15, hi = lane >> 4;
  const int s7 = lo & 7;
  const int n = blockIdx.x;
  const int xcd = n & 7, slot = n >> 3;
  const int bh = xcd + 8 * (slot >> 4);
  const int xp = slot & 15;
  const int b = bh >> 4, h = bh & 15;
  const float scale = 0.08838834764831845f;
  const float NEG_INF = -__builtin_inff();

  const bf16* vsrc[4];
  const bf16* ksrc[4];
  #pragma unroll
  for (int i = 0; i < 4; ++i) {
    const int gv = i * 256 + tid;
    vsrc[i] = VT + (size_t)(bh * 128 + (gv >> 3)) * L + (gv & 7) * 8;
    const int gk = i * 256 + tid;
    ksrc[i] = Kswz + (size_t)(b * L + (gk >> 4)) * DM + h * 128 + (gk & 15) * 8;
  }

  for (int pass = 0; pass < 2; ++pass) {
    const int tile = pass ? xp : (31 - xp);
    const int qrow = tile * 64 + w * 16;

    bf16x8 qf[4];
    {
      const bf16* qb = Q + (size_t)(b * L + qrow + lo) * DM + h * 128;
      #pragma unroll
      for (int ds = 0; ds < 4; ++ds) qf[ds] = *(const bf16x8*)(qb + ds * 32 + hi * 8);
    }

    float mrow[4] = {NEG_INF, NEG_INF, NEG_INF, NEG_INF};
    float lrow[4] = {0.f, 0.f, 0.f, 0.f};
    f32x4 oacc[8] = {};

    #pragma unroll
    for (int i = 0; i < 4; ++i) {
      gload16(ksrc[i], &Kt[0][(i * 256 + w * 64) * 8]);
      gload16(vsrc[i], &Vt[0][(i * 256 + w * 64) * 8]);
    }
    __syncthreads();

    const int nkt = tile + 1;
    for (int kt = 0; kt < nkt; ++kt) {
      const int buf = kt & 1;
      if (kt + 1 < nkt) {
        #pragma unroll
        for (int i = 0; i < 4; ++i) {
          gload16(ksrc[i] + (size_t)(kt + 1) * 64 * DM, &Kt[buf ^ 1][(i * 256 + w * 64) * 8]);
          gload16(vsrc[i] + (kt + 1) * 64,              &Vt[buf ^ 1][(i * 256 + w * 64) * 8]);
        }
      }

      int mk[4];
      #pragma unroll
      for (int kb = 0; kb < 4; ++kb) mk[kb] = mask[b * L + kt * 64 + kb * 16 + lo];

      f32x4 S[4];
      __builtin_amdgcn_s_setprio(1);
      #pragma unroll
      for (int kb = 0; kb < 4; ++kb) {
        f32x4 s = {};
        #pragma unroll
        for (int ds = 0; ds < 4; ++ds) {
          const bf16x8 kf = *(const bf16x8*)&Kt[buf][(kb * 16 + lo) * 128 + (((ds * 4 + hi) ^ lo) * 8)];
          s = __builtin_amdgcn_mfma_f32_16x16x32_bf16(qf[ds], kf, s, 0, 0, 0);
        }
        S[kb] = s;
      }
      __builtin_amdgcn_s_setprio(0);

      #pragma unroll
      for (int kb = 0; kb < 4; ++kb) {
        const int kidx = kt * 64 + kb * 16 + lo;
        #pragma unroll
        for (int j = 0; j < 4; ++j) {
          const float sv = S[kb][j] * scale;
          S[kb][j] = (mk[kb] != 0 && kidx <= qrow + hi * 4 + j) ? sv : NEG_INF;
        }
      }

      // ---- online softmax with T13 defer-max (rescale only if tile max
      //      exceeds running max by > 8; P bounded by e^8, exact math) ----
      float p[4][4];
      #pragma unroll
      for (int j = 0; j < 4; ++j) {
        float tm = fmaxf(fmaxf(S[0][j], S[1][j]), fmaxf(S[2][j], S[3][j]));
        tm = fmaxf(tm, __shfl_xor(tm, 1, 64));
        tm = fmaxf(tm, __shfl_xor(tm, 2, 64));
        tm = fmaxf(tm, __shfl_xor(tm, 4, 64));
        tm = fmaxf(tm, __shfl_xor(tm, 8, 64));
        float alpha = 1.0f;
        if (tm - 8.0f > mrow[j]) {
          alpha = (mrow[j] == NEG_INF) ? 0.0f : __expf(mrow[j] - tm);
          mrow[j] = tm;
        }
        const float mn2 = (mrow[j] == NEG_INF) ? 0.0f : mrow[j];
        float ps = 0.f;
        #pragma unroll
        for (int kb = 0; kb < 4; ++kb) { p[kb][j] = __expf(S[kb][j] - mn2); ps += p[kb][j]; }
        ps += __shfl_xor(ps, 1, 64);
        ps += __shfl_xor(ps, 2, 64);
        ps += __shfl_xor(ps, 4, 64);
        ps += __shfl_xor(ps, 8, 64);
        lrow[j] = lrow[j] * alpha + ps;
        if (alpha != 1.0f) {
          #pragma unroll
          for (int n2 = 0; n2 < 8; ++n2) oacc[n2][j] *= alpha;
        }
      }

      #pragma unroll
      for (int kb = 0; kb < 4; ++kb)
        #pragma unroll
        for (int j = 0; j < 4; ++j) {
          const int row = hi * 4 + j;
          Plds[w][row * 64 + ((((kb * 2 + (lo >> 3)) ^ (row & 7))) << 3) + (lo & 7)] = (bf16)p[kb][j];
        }

      __builtin_amdgcn_s_setprio(1);
      #pragma unroll
      for (int ks = 0; ks < 2; ++ks) {
        const bf16x8 pa = *(const bf16x8*)&Plds[w][lo * 64 + (((ks * 4 + hi) ^ s7) << 3)];
        #pragma unroll
        for (int n2 = 0; n2 < 8; ++n2) {
          const int r = n2 * 16 + lo;
          const bf16x8 vf = *(const bf16x8*)&Vt[buf][r * 64 + (((ks * 4 + hi) ^ s7) << 3)];
          oacc[n2] = __builtin_amdgcn_mfma_f32_16x16x32_bf16(pa, vf, oacc[n2], 0, 0, 0);
        }
      }
      __builtin_amdgcn_s_setprio(0);

      __syncthreads();
    }

    float inv[4];
    #pragma unroll
    for (int j = 0; j < 4; ++j) inv[j] = (lrow[j] > 0.f) ? 1.f / lrow[j] : 0.f;
    bf16* ob = O + (size_t)(b * L + qrow) * DM + h * 128;
    #pragma unroll
    for (int n2 = 0; n2 < 8; ++n2)
      #pragma unroll
      for (int j = 0; j < 4; ++j)
        ob[(size_t)(hi * 4 + j) * DM + n2 * 16 + lo] = (bf16)(oacc[n2][j] * inv[j]);
  }
}

// ---------------------------------------------------------------------------
extern "C" void kernel_launch(void* const* d_in, const int* in_sizes, int n_in,
                              void* d_out, int out_size, void* d_ws, size_t ws_size,
                              hipStream_t stream)
{
  (void)in_sizes; (void)n_in; (void)out_size; (void)ws_size;
  const float* x        = (const float*)d_in[0];
  const float* rope_cos = (const float*)d_in[1];
  const float* rope_sin = (const float*)d_in[2];
  const int*   mask     = (const int*)d_in[3];
  const float* w_norm1  = (const float*)d_in[4];
  const float* w_norm2  = (const float*)d_in[5];
  const float* wq       = (const float*)d_in[6];
  const float* wk       = (const float*)d_in[7];
  const float* wv       = (const float*)d_in[8];
  const float* wo       = (const float*)d_in[9];
  const float* w_ff1    = (const float*)d_in[10];
  const float* w_ff2    = (const float*)d_in[11];
  float* out = (float*)d_out;

  const int M = 4096, D = 2048, FFD = 8192;
  char* ws = (char*)d_ws;
  const size_t WSLAB = 8388608ull;    // 2048*2048*2 B
  const size_t XNB   = 16777216ull;   // 4096*2048*2 B
  bf16* wqt  = (bf16*)(ws);           // wqt|wkt|wvt contiguous = [6144][2048]
  bf16* wkt  = (bf16*)(ws + WSLAB);
  bf16* wvt  = (bf16*)(ws + 2 * WSLAB);
  bf16* wot  = (bf16*)(ws + 3 * WSLAB);
  char* pool = ws + 4 * WSLAB;
  bf16* xn   = (bf16*)(pool);
  bf16* qb   = (bf16*)(pool + XNB);
  bf16* kb   = (bf16*)(pool + 2 * XNB);
  bf16* vb   = (bf16*)(pool + 3 * XNB);
  bf16* ao   = (bf16*)(pool + 4 * XNB);
  bf16* vt   = (bf16*)(pool);               // reuses xn after QKV GEMM
  bf16* kswz = (bf16*)(pool + 3 * XNB);     // reuses vb after v_transpose
  bf16* ff1t = (bf16*)(ws);                 // reuses wq_t..wo_t after WO GEMM
  bf16* hmid = (bf16*)(pool);               // reuses vt|qb|kb after attention
  bf16* ff2t = (bf16*)(ws);                 // reuses ff1_t after FF1
  bf16* xn2  = (bf16*)(pool + 4 * XNB);     // reuses ao after WO GEMM

  const dim3 tb(32, 8);

  rmsnorm_to_bf16<<<M, 256, 0, stream>>>(x, w_norm1, xn);
  transpose4_to_bf16<<<dim3(D / 32, D / 32, 4), tb, 0, stream>>>(
      wq, wk, wv, wo, wqt, wkt, wvt, wot);

  // fused QKV on gemm128: 768 blocks = 3 exact rounds; Bt = [6144][2048]
  gemm128<3><<<(M / 128) * (6144 / 256), 512, 0, stream>>>(xn, wqt, qb, nullptr, M, 6144, D);

  // xn dead after QKV GEMM; vt overwrites it
  v_transpose<<<dim3(2048 / 32, 128 / 32, 32), tb, 0, stream>>>(vb, vt);

  // vb dead after v_transpose; kswz overwrites it
  rope_qk<<<2048, 256, 0, stream>>>(qb, kb, kswz, rope_cos, rope_sin);

  attn_fwd<<<512, 256, 0, stream>>>(qb, kswz, vt, mask, ao);

  // WO on the 128x256 pipeline (256 blocks = 1 full round)
  gemm128<1><<<(M / 128) * (D / 256), 512, 0, stream>>>(ao, wot, out, x, M, D, D);

  rmsnorm_to_bf16<<<M, 256, 0, stream>>>(out, w_norm2, xn2);

  transpose_to_bf16<<<dim3(FFD / 32, D / 32), tb, 0, stream>>>(w_ff1, ff1t, D, FFD);
  gemm256<2><<<(M / 256) * (FFD / 256), 512, 0, stream>>>(xn2, ff1t, hmid, nullptr, M, FFD, D);

  transpose_to_bf16<<<dim3(D / 32, FFD / 32), tb, 0, stream>>>(w_ff2, ff2t, FFD, D);
  gemm128<1><<<(M / 128) * (D / 256), 512, 0, stream>>>(hmid, ff2t, out, out, M, D, FFD);
}

// Round 18
// 628.893 us; speedup vs baseline: 1.0383x; 1.0383x over previous
//
#include <hip/hip_runtime.h>

// ---------------------------------------------------------------------------
// DecoderBlock on MI355X (gfx950).  B=2, L=2048, D=2048, H=16, DH=128, FF=8192
// Round 18: FINAL — revert to R16 (best measured: 629.4 us).  R17's defer-max
// regressed (lane-divergent skip branch, missing __all vote).  This file is
// byte-identical to the passing R16 kernel.
// Session summary: 1013 -> 629 us via pipelined 256x/128x GEMMs (T1-T5,
// deep prefetch, source-side T2 swizzle, conflict-free LDS), two-pass
// balanced flash attention with K/V LDS dbuf, fused QKV, fused transposes.
// GEMM plateau at ~34% MfmaUtil held against 7 independent lever axes.
// ---------------------------------------------------------------------------

typedef __bf16 bf16;
typedef __bf16 bf16x8 __attribute__((ext_vector_type(8)));
typedef float  f32x4  __attribute__((ext_vector_type(4)));

__device__ __forceinline__ void gload16(const void* g, void* l) {
  __builtin_amdgcn_global_load_lds((const __attribute__((address_space(1))) void*)g,
                                   (__attribute__((address_space(3))) void*)l,
                                   16, 0, 0);
}

#define CBAR asm volatile("" ::: "memory")
#define WAITV(N) asm volatile("s_waitcnt vmcnt(" #N ")" ::: "memory")
#define LGKM0 asm volatile("s_waitcnt lgkmcnt(0)" ::: "memory")
#define BARR { CBAR; __builtin_amdgcn_s_barrier(); CBAR; }

// ------------------------------ RMSNorm (f32 -> bf16, linear) --------------
__global__ __launch_bounds__(256) void rmsnorm_to_bf16(
    const float* __restrict__ x, const float* __restrict__ w, bf16* __restrict__ out)
{
  const int D = 2048;
  const int row = blockIdx.x;
  const int tid = threadIdx.x;
  const float* xr = x + (size_t)row * D;
  float4 a = ((const float4*)xr)[tid * 2];
  float4 c = ((const float4*)xr)[tid * 2 + 1];
  float ss = a.x*a.x + a.y*a.y + a.z*a.z + a.w*a.w
           + c.x*c.x + c.y*c.y + c.z*c.z + c.w*c.w;
  #pragma unroll
  for (int m = 1; m < 64; m <<= 1) ss += __shfl_xor(ss, m, 64);
  __shared__ float red[4];
  if ((tid & 63) == 0) red[tid >> 6] = ss;
  __syncthreads();
  float tot = red[0] + red[1] + red[2] + red[3];
  float rms = rsqrtf(tot * (1.0f / D) + 1.1920929e-7f);
  const float* wr = w + tid * 8;
  float vals[8] = {a.x, a.y, a.z, a.w, c.x, c.y, c.z, c.w};
  bf16x8 o;
  #pragma unroll
  for (int j = 0; j < 8; ++j) o[j] = (bf16)(vals[j] * rms * wr[j]);
  *(bf16x8*)(out + (size_t)row * D + tid * 8) = o;
}

// --------------------- transpose + convert f32[R][C] -> bf16[C][R] ---------
__global__ __launch_bounds__(256) void transpose_to_bf16(
    const float* __restrict__ in, bf16* __restrict__ out, int R, int C)
{
  __shared__ float tile[32][33];
  const int tx = threadIdx.x, ty = threadIdx.y;      // 32 x 8
  const int c0 = blockIdx.x * 32, r0 = blockIdx.y * 32;
  #pragma unroll
  for (int i = 0; i < 4; ++i)
    tile[ty + i * 8][tx] = in[(size_t)(r0 + ty + i * 8) * C + c0 + tx];
  __syncthreads();
  #pragma unroll
  for (int i = 0; i < 4; ++i)
    out[(size_t)(c0 + ty + i * 8) * R + r0 + tx] = (bf16)tile[tx][ty + i * 8];
}

// ----- fused 4x (2048x2048) transpose: z selects {wq,wk,wv,wo} -------------
__global__ __launch_bounds__(256) void transpose4_to_bf16(
    const float* __restrict__ w0, const float* __restrict__ w1,
    const float* __restrict__ w2, const float* __restrict__ w3,
    bf16* __restrict__ o0, bf16* __restrict__ o1,
    bf16* __restrict__ o2, bf16* __restrict__ o3)
{
  const int R = 2048, C = 2048;
  __shared__ float tile[32][33];
  const int tx = threadIdx.x, ty = threadIdx.y;      // 32 x 8
  const int c0 = blockIdx.x * 32, r0 = blockIdx.y * 32;
  const int z = blockIdx.z;
  const float* in = (z == 0) ? w0 : (z == 1) ? w1 : (z == 2) ? w2 : w3;
  bf16* out = (z == 0) ? o0 : (z == 1) ? o1 : (z == 2) ? o2 : o3;
  #pragma unroll
  for (int i = 0; i < 4; ++i)
    tile[ty + i * 8][tx] = in[(size_t)(r0 + ty + i * 8) * C + c0 + tx];
  __syncthreads();
  #pragma unroll
  for (int i = 0; i < 4; ++i)
    out[(size_t)(c0 + ty + i * 8) * R + r0 + tx] = (bf16)tile[tx][ty + i * 8];
}

// --------------- V[b*L+key][h*128+dh] -> VT[(bh*128+dh)][key'] (bf16) ------
__global__ __launch_bounds__(256) void v_transpose(
    const bf16* __restrict__ v, bf16* __restrict__ vt)
{
  const int L = 2048, DM = 2048;
  __shared__ bf16 tile[32][33];
  const int tx = threadIdx.x, ty = threadIdx.y;      // 32 x 8
  const int k0 = blockIdx.x * 32;
  const int d0 = blockIdx.y * 32;
  const int bh = blockIdx.z;
  const int b = bh >> 4, h = bh & 15;
  #pragma unroll
  for (int i = 0; i < 4; ++i)
    tile[ty + i * 8][tx] = v[(size_t)(b * L + k0 + ty + i * 8) * DM + h * 128 + d0 + tx];
  __syncthreads();
  #pragma unroll
  for (int i = 0; i < 4; ++i) {
    const int d = d0 + ty + i * 8;
    const int key = k0 + tx;
    const int keysw = (key & ~63) | (((((key >> 3) & 7) ^ (d & 7)) << 3)) | (key & 7);
    vt[(size_t)(bh * 128 + d) * L + keysw] = tile[tx][ty + i * 8];
  }
}

// ------------- 256x256 4-phase GEMM, 7-unit deep prefetch (BK=64) ----------
// R11 schedule + hoisted addresses.  EPI: 2 = silu bf16
template<int EPI>
__global__ __launch_bounds__(512, 1) void gemm256(
    const bf16* __restrict__ A, const bf16* __restrict__ Bt,
    void* Cout, const float* __restrict__ resid, int M, int N, int K)
{
  __shared__ bf16 sA[2][2][128 * 64];   // 64 KB ; buf stride 32768B, rh 16384B
  __shared__ bf16 sB[2][2][128 * 64];   // 64 KB

  const int tid = threadIdx.x, lane = tid & 63, w = tid >> 6;
  const int wm = w >> 2, wn = w & 3;
  const int lo = lane & 15, hi = lane >> 4;
  const int lo7 = lo & 7;

  const int nbn = N >> 8;
  const int nwg = gridDim.x;
  int swz = blockIdx.x;
  if ((nwg & 7) == 0) { const int cpx = nwg >> 3; swz = (swz & 7) * cpx + (swz >> 3); }
  const int bm = swz / nbn, bn = swz % nbn;

  const int r0 = tid >> 3,         s0 = (tid & 7) ^ (r0 & 7);
  const int r1 = (512 + tid) >> 3, s1 = ((512 + tid) & 7) ^ (r1 & 7);
  const bf16* Ab = A  + (size_t)(bm * 256) * K;
  const bf16* Bb = Bt + (size_t)(bn * 256) * K;
  const size_t o0 = (size_t)r0 * K + s0 * 8;
  const size_t o1 = (size_t)r1 * K + s1 * 8;
  const int dst0 = (w * 64) * 8, dst1 = (512 + w * 64) * 8;
  const size_t rhK = (size_t)128 * K;

  unsigned offA[2][4], offB[2][2];
  #pragma unroll
  for (int ks = 0; ks < 2; ++ks) {
    #pragma unroll
    for (int m = 0; m < 4; ++m)
      offA[ks][m] = (unsigned)((((wm * 64 + m * 16 + lo) * 64) + (((ks * 4 + hi) ^ lo7) << 3)) * 2);
    #pragma unroll
    for (int nj = 0; nj < 2; ++nj)
      offB[ks][nj] = (unsigned)((((wn * 32 + nj * 16 + lo) * 64) + (((ks * 4 + hi) ^ lo7) << 3)) * 2);
  }

  const bf16* pA1_0 = Ab + rhK + 64 + o0;  const bf16* pA1_1 = Ab + rhK + 64 + o1;
  const bf16* pA0_0 = Ab + 128 + o0;       const bf16* pA0_1 = Ab + 128 + o1;
  const bf16* pB0_0 = Bb + 128 + o0;       const bf16* pB0_1 = Bb + 128 + o1;
  const bf16* pB1_0 = Bb + rhK + 128 + o0; const bf16* pB1_1 = Bb + rhK + 128 + o1;

  bf16x8 a0[2][4], a1[2][4], b0[2][2], b1[2][2];
  f32x4 acc[8][4] = {};
  const int NT = K >> 6;

  auto loadA = [&](bf16x8 (&d)[2][4], int b, int rh) {
    const char* base = (const char*)(&sA[0][0][0]) + b * 32768 + rh * 16384;
    #pragma unroll
    for (int ks = 0; ks < 2; ++ks)
      #pragma unroll
      for (int m = 0; m < 4; ++m)
        d[ks][m] = *(const bf16x8*)(base + offA[ks][m]);
  };
  auto loadB = [&](bf16x8 (&d)[2][2], int b, int rh) {
    const char* base = (const char*)(&sB[0][0][0]) + b * 32768 + rh * 16384;
    #pragma unroll
    for (int ks = 0; ks < 2; ++ks)
      #pragma unroll
      for (int nj = 0; nj < 2; ++nj)
        d[ks][nj] = *(const bf16x8*)(base + offB[ks][nj]);
  };
  auto mfma16 = [&](bf16x8 (&a)[2][4], bf16x8 (&bf)[2][2], int mb, int nb2) {
    __builtin_amdgcn_s_setprio(1);
    #pragma unroll
    for (int ks = 0; ks < 2; ++ks)
      #pragma unroll
      for (int m = 0; m < 4; ++m)
        #pragma unroll
        for (int nj = 0; nj < 2; ++nj)
          acc[mb + m][nb2 + nj] = __builtin_amdgcn_mfma_f32_16x16x32_bf16(
              a[ks][m], bf[ks][nj], acc[mb + m][nb2 + nj], 0, 0, 0);
    __builtin_amdgcn_s_setprio(0);
  };

  {
    gload16(Ab + o0, &sA[0][0][dst0]);        gload16(Ab + o1, &sA[0][0][dst1]);
    gload16(Bb + o0, &sB[0][0][dst0]);        gload16(Bb + o1, &sB[0][0][dst1]);
    gload16(Bb + rhK + o0, &sB[0][1][dst0]);  gload16(Bb + rhK + o1, &sB[0][1][dst1]);
    gload16(Ab + rhK + o0, &sA[0][1][dst0]);  gload16(Ab + rhK + o1, &sA[0][1][dst1]);
    gload16(Ab + 64 + o0, &sA[1][0][dst0]);   gload16(Ab + 64 + o1, &sA[1][0][dst1]);
    gload16(Bb + 64 + o0, &sB[1][0][dst0]);   gload16(Bb + 64 + o1, &sB[1][0][dst1]);
    gload16(Bb + rhK + 64 + o0, &sB[1][1][dst0]); gload16(Bb + rhK + 64 + o1, &sB[1][1][dst1]);
  }
  WAITV(6);
  BARR;

  for (int t = 0; t < NT; ++t) {
    const int buf = t & 1, nb = buf ^ 1;
    const int u = 4 * t;
    loadA(a0, buf, 0);
    loadB(b0, buf, 0);
    if (u + 7 < 4 * NT) { gload16(pA1_0, &sA[nb][1][dst0]); gload16(pA1_1, &sA[nb][1][dst1]); }
    BARR; LGKM0;
    mfma16(a0, b0, 0, 0);
    BARR;
    loadB(b1, buf, 1);
    if (u + 8 < 4 * NT) { gload16(pA0_0, &sA[buf][0][dst0]); gload16(pA0_1, &sA[buf][0][dst1]); }
    BARR; LGKM0;
    mfma16(a0, b1, 0, 2);
    BARR;
    loadA(a1, buf, 1);
    if (u + 9 < 4 * NT) { gload16(pB0_0, &sB[buf][0][dst0]); gload16(pB0_1, &sB[buf][0][dst1]); }
    BARR; LGKM0;
    mfma16(a1, b1, 4, 2);
    BARR;
    if (u + 10 < 4 * NT) { gload16(pB1_0, &sB[buf][1][dst0]); gload16(pB1_1, &sB[buf][1][dst1]); }
    mfma16(a1, b0, 4, 0);
    if (t < NT - 2) { WAITV(6); } else if (t == NT - 2) { WAITV(0); }
    BARR;
    pA1_0 += 64; pA1_1 += 64; pA0_0 += 64; pA0_1 += 64;
    pB0_0 += 64; pB0_1 += 64; pB1_0 += 64; pB1_1 += 64;
  }

  #pragma unroll
  for (int mi = 0; mi < 8; ++mi) {
    #pragma unroll
    for (int j = 0; j < 4; ++j) {
      const size_t row = (size_t)(bm * 256 + (mi >> 2) * 128 + wm * 64 + (mi & 3) * 16 + hi * 4 + j);
      #pragma unroll
      for (int ni = 0; ni < 4; ++ni) {
        const int col = bn * 256 + (ni >> 1) * 128 + wn * 32 + (ni & 1) * 16 + lo;
        const float v = acc[mi][ni][j];
        if constexpr (EPI == 2) {
          ((bf16*)Cout)[row * (size_t)N + col] = (bf16)(v / (1.0f + __expf(-v)));
        } else {
          ((bf16*)Cout)[(size_t)(col >> 11) * 8388608 + row * 2048 + (col & 2047)] = (bf16)v;
        }
      }
    }
  }
}

// ------------- 128x256 2-phase GEMM, 5-unit deep prefetch (BK=64) ----------
// R11 schedule + hoisted addresses.  EPI: 1 = f32 + resid; 3 = q/k/v slabs
template<int EPI>
__global__ __launch_bounds__(512, 1) void gemm128(
    const bf16* __restrict__ A, const bf16* __restrict__ Bt,
    void* Cout, const float* __restrict__ resid, int M, int N, int K)
{
  __shared__ bf16 sA[2][128 * 64];      // 32 KB ; buf stride 16384B
  __shared__ bf16 sB[2][2][128 * 64];   // 64 KB ; buf stride 32768B, nh 16384B

  const int tid = threadIdx.x, lane = tid & 63, w = tid >> 6;
  const int wm = w >> 2, wn = w & 3;
  const int lo = lane & 15, hi = lane >> 4;
  const int lo7 = lo & 7;

  const int nbn = N >> 8;
  const int nwg = gridDim.x;
  int swz = blockIdx.x;
  if ((nwg & 7) == 0) { const int cpx = nwg >> 3; swz = (swz & 7) * cpx + (swz >> 3); }
  const int bm = swz / nbn, bn = swz % nbn;

  const int r0 = tid >> 3,         s0 = (tid & 7) ^ (r0 & 7);
  const int r1 = (512 + tid) >> 3, s1 = ((512 + tid) & 7) ^ (r1 & 7);
  const bf16* Ab = A  + (size_t)(bm * 128) * K;
  const bf16* Bb = Bt + (size_t)(bn * 256) * K;
  const size_t o0 = (size_t)r0 * K + s0 * 8;
  const size_t o1 = (size_t)r1 * K + s1 * 8;
  const int dst0 = (w * 64) * 8, dst1 = (512 + w * 64) * 8;
  const size_t nhK = (size_t)128 * K;

  unsigned offA[2][4], offB[2][2];
  #pragma unroll
  for (int ks = 0; ks < 2; ++ks) {
    #pragma unroll
    for (int m = 0; m < 4; ++m)
      offA[ks][m] = (unsigned)((((wm * 64 + m * 16 + lo) * 64) + (((ks * 4 + hi) ^ lo7) << 3)) * 2);
    #pragma unroll
    for (int nj = 0; nj < 2; ++nj)
      offB[ks][nj] = (unsigned)((((wn * 32 + nj * 16 + lo) * 64) + (((ks * 4 + hi) ^ lo7) << 3)) * 2);
  }

  const bf16* pB1_0 = Bb + nhK + 64 + o0;  const bf16* pB1_1 = Bb + nhK + 64 + o1;
  const bf16* pA_0  = Ab + 128 + o0;       const bf16* pA_1  = Ab + 128 + o1;
  const bf16* pB0_0 = Bb + 128 + o0;       const bf16* pB0_1 = Bb + 128 + o1;

  bf16x8 afA[2][4], b0[2][2], b1[2][2];
  f32x4 acc[4][4] = {};
  const int NT = K >> 6;

  auto loadA = [&](int b) {
    const char* base = (const char*)(&sA[0][0]) + b * 16384;
    #pragma unroll
    for (int ks = 0; ks < 2; ++ks)
      #pragma unroll
      for (int m = 0; m < 4; ++m)
        afA[ks][m] = *(const bf16x8*)(base + offA[ks][m]);
  };
  auto loadB = [&](bf16x8 (&d)[2][2], int b, int nh) {
    const char* base = (const char*)(&sB[0][0][0]) + b * 32768 + nh * 16384;
    #pragma unroll
    for (int ks = 0; ks < 2; ++ks)
      #pragma unroll
      for (int nj = 0; nj < 2; ++nj)
        d[ks][nj] = *(const bf16x8*)(base + offB[ks][nj]);
  };
  auto mfma16 = [&](bf16x8 (&bf)[2][2], int nb2) {
    __builtin_amdgcn_s_setprio(1);
    #pragma unroll
    for (int ks = 0; ks < 2; ++ks)
      #pragma unroll
      for (int m = 0; m < 4; ++m)
        #pragma unroll
        for (int nj = 0; nj < 2; ++nj)
          acc[m][nb2 + nj] = __builtin_amdgcn_mfma_f32_16x16x32_bf16(
              afA[ks][m], bf[ks][nj], acc[m][nb2 + nj], 0, 0, 0);
    __builtin_amdgcn_s_setprio(0);
  };

  {
    gload16(Ab + o0, &sA[0][dst0]);           gload16(Ab + o1, &sA[0][dst1]);
    gload16(Bb + o0, &sB[0][0][dst0]);        gload16(Bb + o1, &sB[0][0][dst1]);
    gload16(Bb + nhK + o0, &sB[0][1][dst0]);  gload16(Bb + nhK + o1, &sB[0][1][dst1]);
    gload16(Ab + 64 + o0, &sA[1][dst0]);      gload16(Ab + 64 + o1, &sA[1][dst1]);
    gload16(Bb + 64 + o0, &sB[1][0][dst0]);   gload16(Bb + 64 + o1, &sB[1][0][dst1]);
  }
  WAITV(4);
  BARR;

  for (int t = 0; t < NT; ++t) {
    const int buf = t & 1, nb = buf ^ 1;
    const int u = 3 * t;
    loadA(buf);
    loadB(b0, buf, 0);
    if (u + 5 < 3 * NT) { gload16(pB1_0, &sB[nb][1][dst0]); gload16(pB1_1, &sB[nb][1][dst1]); }
    BARR; LGKM0;
    mfma16(b0, 0);
    BARR;
    loadB(b1, buf, 1);
    if (u + 6 < 3 * NT) { gload16(pA_0, &sA[buf][dst0]); gload16(pA_1, &sA[buf][dst1]); }
    if (u + 7 < 3 * NT) { gload16(pB0_0, &sB[buf][0][dst0]); gload16(pB0_1, &sB[buf][0][dst1]); }
    BARR; LGKM0;
    mfma16(b1, 2);
    if (t < NT - 2) { WAITV(4); } else if (t == NT - 2) { WAITV(0); }
    BARR;
    pB1_0 += 64; pB1_1 += 64; pA_0 += 64; pA_1 += 64; pB0_0 += 64; pB0_1 += 64;
  }

  #pragma unroll
  for (int mi = 0; mi < 4; ++mi) {
    #pragma unroll
    for (int j = 0; j < 4; ++j) {
      const size_t row = (size_t)(bm * 128 + wm * 64 + mi * 16 + hi * 4 + j);
      #pragma unroll
      for (int ni = 0; ni < 4; ++ni) {
        const int col = bn * 256 + (ni >> 1) * 128 + wn * 32 + (ni & 1) * 16 + lo;
        const float v = acc[mi][ni][j];
        if constexpr (EPI == 1) {
          const size_t ro = row * (size_t)N;
          ((float*)Cout)[ro + col] = v + resid[ro + col];
        } else {
          ((bf16*)Cout)[(size_t)(col >> 11) * 8388608 + row * 2048 + (col & 2047)] = (bf16)v;
        }
      }
    }
  }
}

// ------------------- RoPE: q in-place; k -> kswz with granule swizzle ------
__global__ __launch_bounds__(256) void rope_qk(
    bf16* q, const bf16* __restrict__ k, bf16* __restrict__ kswz,
    const float* __restrict__ cs, const float* __restrict__ sn)
{
  const int L = 2048, DM = 2048;
  const int idx = blockIdx.x * 256 + threadIdx.x;
  const int m = idx >> 7;
  const int rem = idx & 127;
  const int h = rem >> 3, t8 = rem & 7;
  const int pos = m & (L - 1);
  const int d0 = t8 * 8;
  const float* cb = cs + (size_t)pos * 128 + d0;
  const float* sb = sn + (size_t)pos * 128 + d0;
  float4 c1a = *(const float4*)(cb);      float4 c1b = *(const float4*)(cb + 4);
  float4 c2a = *(const float4*)(cb + 64); float4 c2b = *(const float4*)(cb + 68);
  float4 s1a = *(const float4*)(sb);      float4 s1b = *(const float4*)(sb + 4);
  float4 s2a = *(const float4*)(sb + 64); float4 s2b = *(const float4*)(sb + 68);
  float c1[8] = {c1a.x,c1a.y,c1a.z,c1a.w,c1b.x,c1b.y,c1b.z,c1b.w};
  float c2[8] = {c2a.x,c2a.y,c2a.z,c2a.w,c2b.x,c2b.y,c2b.z,c2b.w};
  float s1[8] = {s1a.x,s1a.y,s1a.z,s1a.w,s1b.x,s1b.y,s1b.z,s1b.w};
  float s2[8] = {s2a.x,s2a.y,s2a.z,s2a.w,s2b.x,s2b.y,s2b.z,s2b.w};
  const size_t base = (size_t)m * DM + h * 128 + d0;

  {
    bf16x8 x1 = *(bf16x8*)(q + base);
    bf16x8 x2 = *(bf16x8*)(q + base + 64);
    bf16x8 o1, o2;
    #pragma unroll
    for (int j = 0; j < 8; ++j) {
      const float a = (float)x1[j], b = (float)x2[j];
      o1[j] = (bf16)(a * c1[j] - b * s1[j]);
      o2[j] = (bf16)(b * c2[j] + a * s2[j]);
    }
    *(bf16x8*)(q + base) = o1;
    *(bf16x8*)(q + base + 64) = o2;
  }
  {
    bf16x8 x1 = *(const bf16x8*)(k + base);
    bf16x8 x2 = *(const bf16x8*)(k + base + 64);
    bf16x8 o1, o2;
    #pragma unroll
    for (int j = 0; j < 8; ++j) {
      const float a = (float)x1[j], b = (float)x2[j];
      o1[j] = (bf16)(a * c1[j] - b * s1[j]);
      o2[j] = (bf16)(b * c2[j] + a * s2[j]);
    }
    const int s = pos & 15;
    const int p1 = t8 ^ s;
    const int p2 = (8 + t8) ^ s;
    bf16* kr = kswz + (size_t)m * DM + h * 128;
    *(bf16x8*)(kr + p1 * 8) = o1;
    *(bf16x8*)(kr + p2 * 8) = o2;
  }
}

// ------------------------------ Flash attention (R13, verified) ------------
__global__ __launch_bounds__(256, 2) void attn_fwd(
    const bf16* __restrict__ Q, const bf16* __restrict__ Kswz,
    const bf16* __restrict__ VT, const int* __restrict__ mask,
    bf16* __restrict__ O)
{
  const int L = 2048, DM = 2048;
  __shared__ bf16 Kt[2][64 * 128];
  __shared__ bf16 Vt[2][128 * 64];
  __shared__ bf16 Plds[4][16 * 64];

  const int tid = threadIdx.x, lane = tid & 63, w = tid >> 6;
  const int lo = lane & 15, hi = lane >> 4;
  const int s7 = lo & 7;
  const int n = blockIdx.x;
  const int xcd = n & 7, slot = n >> 3;
  const int bh = xcd + 8 * (slot >> 4);
  const int xp = slot & 15;
  const int b = bh >> 4, h = bh & 15;
  const float scale = 0.08838834764831845f;
  const float NEG_INF = -__builtin_inff();

  const bf16* vsrc[4];
  const bf16* ksrc[4];
  #pragma unroll
  for (int i = 0; i < 4; ++i) {
    const int gv = i * 256 + tid;
    vsrc[i] = VT + (size_t)(bh * 128 + (gv >> 3)) * L + (gv & 7) * 8;
    const int gk = i * 256 + tid;
    ksrc[i] = Kswz + (size_t)(b * L + (gk >> 4)) * DM + h * 128 + (gk & 15) * 8;
  }

  for (int pass = 0; pass < 2; ++pass) {
    const int tile = pass ? xp : (31 - xp);
    const int qrow = tile * 64 + w * 16;

    bf16x8 qf[4];
    {
      const bf16* qb = Q + (size_t)(b * L + qrow + lo) * DM + h * 128;
      #pragma unroll
      for (int ds = 0; ds < 4; ++ds) qf[ds] = *(const bf16x8*)(qb + ds * 32 + hi * 8);
    }

    float mrow[4] = {NEG_INF, NEG_INF, NEG_INF, NEG_INF};
    float lrow[4] = {0.f, 0.f, 0.f, 0.f};
    f32x4 oacc[8] = {};

    #pragma unroll
    for (int i = 0; i < 4; ++i) {
      gload16(ksrc[i], &Kt[0][(i * 256 + w * 64) * 8]);
      gload16(vsrc[i], &Vt[0][(i * 256 + w * 64) * 8]);
    }
    __syncthreads();

    const int nkt = tile + 1;
    for (int kt = 0; kt < nkt; ++kt) {
      const int buf = kt & 1;
      if (kt + 1 < nkt) {
        #pragma unroll
        for (int i = 0; i < 4; ++i) {
          gload16(ksrc[i] + (size_t)(kt + 1) * 64 * DM, &Kt[buf ^ 1][(i * 256 + w * 64) * 8]);
          gload16(vsrc[i] + (kt + 1) * 64,              &Vt[buf ^ 1][(i * 256 + w * 64) * 8]);
        }
      }

      int mk[4];
      #pragma unroll
      for (int kb = 0; kb < 4; ++kb) mk[kb] = mask[b * L + kt * 64 + kb * 16 + lo];

      f32x4 S[4];
      __builtin_amdgcn_s_setprio(1);
      #pragma unroll
      for (int kb = 0; kb < 4; ++kb) {
        f32x4 s = {};
        #pragma unroll
        for (int ds = 0; ds < 4; ++ds) {
          const bf16x8 kf = *(const bf16x8*)&Kt[buf][(kb * 16 + lo) * 128 + (((ds * 4 + hi) ^ lo) * 8)];
          s = __builtin_amdgcn_mfma_f32_16x16x32_bf16(qf[ds], kf, s, 0, 0, 0);
        }
        S[kb] = s;
      }
      __builtin_amdgcn_s_setprio(0);

      #pragma unroll
      for (int kb = 0; kb < 4; ++kb) {
        const int kidx = kt * 64 + kb * 16 + lo;
        #pragma unroll
        for (int j = 0; j < 4; ++j) {
          const float sv = S[kb][j] * scale;
          S[kb][j] = (mk[kb] != 0 && kidx <= qrow + hi * 4 + j) ? sv : NEG_INF;
        }
      }

      float p[4][4];
      #pragma unroll
      for (int j = 0; j < 4; ++j) {
        float tm = fmaxf(fmaxf(S[0][j], S[1][j]), fmaxf(S[2][j], S[3][j]));
        tm = fmaxf(tm, __shfl_xor(tm, 1, 64));
        tm = fmaxf(tm, __shfl_xor(tm, 2, 64));
        tm = fmaxf(tm, __shfl_xor(tm, 4, 64));
        tm = fmaxf(tm, __shfl_xor(tm, 8, 64));
        const float mn = fmaxf(mrow[j], tm);
        const float mn2 = (mn == NEG_INF) ? 0.f : mn;
        const float alpha = __expf(mrow[j] - mn2);
        float ps = 0.f;
        #pragma unroll
        for (int kb = 0; kb < 4; ++kb) { p[kb][j] = __expf(S[kb][j] - mn2); ps += p[kb][j]; }
        ps += __shfl_xor(ps, 1, 64);
        ps += __shfl_xor(ps, 2, 64);
        ps += __shfl_xor(ps, 4, 64);
        ps += __shfl_xor(ps, 8, 64);
        lrow[j] = lrow[j] * alpha + ps;
        mrow[j] = mn;
        #pragma unroll
        for (int n2 = 0; n2 < 8; ++n2) oacc[n2][j] *= alpha;
      }

      #pragma unroll
      for (int kb = 0; kb < 4; ++kb)
        #pragma unroll
        for (int j = 0; j < 4; ++j) {
          const int row = hi * 4 + j;
          Plds[w][row * 64 + ((((kb * 2 + (lo >> 3)) ^ (row & 7))) << 3) + (lo & 7)] = (bf16)p[kb][j];
        }

      __builtin_amdgcn_s_setprio(1);
      #pragma unroll
      for (int ks = 0; ks < 2; ++ks) {
        const bf16x8 pa = *(const bf16x8*)&Plds[w][lo * 64 + (((ks * 4 + hi) ^ s7) << 3)];
        #pragma unroll
        for (int n2 = 0; n2 < 8; ++n2) {
          const int r = n2 * 16 + lo;
          const bf16x8 vf = *(const bf16x8*)&Vt[buf][r * 64 + (((ks * 4 + hi) ^ s7) << 3)];
          oacc[n2] = __builtin_amdgcn_mfma_f32_16x16x32_bf16(pa, vf, oacc[n2], 0, 0, 0);
        }
      }
      __builtin_amdgcn_s_setprio(0);

      __syncthreads();
    }

    float inv[4];
    #pragma unroll
    for (int j = 0; j < 4; ++j) inv[j] = (lrow[j] > 0.f) ? 1.f / lrow[j] : 0.f;
    bf16* ob = O + (size_t)(b * L + qrow) * DM + h * 128;
    #pragma unroll
    for (int n2 = 0; n2 < 8; ++n2)
      #pragma unroll
      for (int j = 0; j < 4; ++j)
        ob[(size_t)(hi * 4 + j) * DM + n2 * 16 + lo] = (bf16)(oacc[n2][j] * inv[j]);
  }
}

// ---------------------------------------------------------------------------
extern "C" void kernel_launch(void* const* d_in, const int* in_sizes, int n_in,
                              void* d_out, int out_size, void* d_ws, size_t ws_size,
                              hipStream_t stream)
{
  (void)in_sizes; (void)n_in; (void)out_size; (void)ws_size;
  const float* x        = (const float*)d_in[0];
  const float* rope_cos = (const float*)d_in[1];
  const float* rope_sin = (const float*)d_in[2];
  const int*   mask     = (const int*)d_in[3];
  const float* w_norm1  = (const float*)d_in[4];
  const float* w_norm2  = (const float*)d_in[5];
  const float* wq       = (const float*)d_in[6];
  const float* wk       = (const float*)d_in[7];
  const float* wv       = (const float*)d_in[8];
  const float* wo       = (const float*)d_in[9];
  const float* w_ff1    = (const float*)d_in[10];
  const float* w_ff2    = (const float*)d_in[11];
  float* out = (float*)d_out;

  const int M = 4096, D = 2048, FFD = 8192;
  char* ws = (char*)d_ws;
  const size_t WSLAB = 8388608ull;    // 2048*2048*2 B
  const size_t XNB   = 16777216ull;   // 4096*2048*2 B
  bf16* wqt  = (bf16*)(ws);           // wqt|wkt|wvt contiguous = [6144][2048]
  bf16* wkt  = (bf16*)(ws + WSLAB);
  bf16* wvt  = (bf16*)(ws + 2 * WSLAB);
  bf16* wot  = (bf16*)(ws + 3 * WSLAB);
  char* pool = ws + 4 * WSLAB;
  bf16* xn   = (bf16*)(pool);
  bf16* qb   = (bf16*)(pool + XNB);
  bf16* kb   = (bf16*)(pool + 2 * XNB);
  bf16* vb   = (bf16*)(pool + 3 * XNB);
  bf16* ao   = (bf16*)(pool + 4 * XNB);
  bf16* vt   = (bf16*)(pool);               // reuses xn after QKV GEMM
  bf16* kswz = (bf16*)(pool + 3 * XNB);     // reuses vb after v_transpose
  bf16* ff1t = (bf16*)(ws);                 // reuses wq_t..wo_t after WO GEMM
  bf16* hmid = (bf16*)(pool);               // reuses vt|qb|kb after attention
  bf16* ff2t = (bf16*)(ws);                 // reuses ff1_t after FF1
  bf16* xn2  = (bf16*)(pool + 4 * XNB);     // reuses ao after WO GEMM

  const dim3 tb(32, 8);

  rmsnorm_to_bf16<<<M, 256, 0, stream>>>(x, w_norm1, xn);
  transpose4_to_bf16<<<dim3(D / 32, D / 32, 4), tb, 0, stream>>>(
      wq, wk, wv, wo, wqt, wkt, wvt, wot);

  // fused QKV on gemm128: 768 blocks = 3 exact rounds; Bt = [6144][2048]
  gemm128<3><<<(M / 128) * (6144 / 256), 512, 0, stream>>>(xn, wqt, qb, nullptr, M, 6144, D);

  // xn dead after QKV GEMM; vt overwrites it
  v_transpose<<<dim3(2048 / 32, 128 / 32, 32), tb, 0, stream>>>(vb, vt);

  // vb dead after v_transpose; kswz overwrites it
  rope_qk<<<2048, 256, 0, stream>>>(qb, kb, kswz, rope_cos, rope_sin);

  attn_fwd<<<512, 256, 0, stream>>>(qb, kswz, vt, mask, ao);

  // WO on the 128x256 pipeline (256 blocks = 1 full round)
  gemm128<1><<<(M / 128) * (D / 256), 512, 0, stream>>>(ao, wot, out, x, M, D, D);

  rmsnorm_to_bf16<<<M, 256, 0, stream>>>(out, w_norm2, xn2);

  transpose_to_bf16<<<dim3(FFD / 32, D / 32), tb, 0, stream>>>(w_ff1, ff1t, D, FFD);
  gemm256<2><<<(M / 256) * (FFD / 256), 512, 0, stream>>>(xn2, ff1t, hmid, nullptr, M, FFD, D);

  transpose_to_bf16<<<dim3(D / 32, FFD / 32), tb, 0, stream>>>(w_ff2, ff2t, FFD, D);
  gemm128<1><<<(M / 128) * (D / 256), 512, 0, stream>>>(hmid, ff2t, out, out, M, D, FFD);
}

// Round 19
// 623.282 us; speedup vs baseline: 1.0476x; 1.0090x over previous
//
#include <hip/hip_runtime.h>

// ---------------------------------------------------------------------------
// DecoderBlock on MI355X (gfx950).  B=2, L=2048, D=2048, H=16, DH=128, FF=8192
// Round 19: R18 (best: 628.9us) + vectorized weight transposes (the last
// scalar-load kernels): 64x64 f32 tiles, float4 loads (16B/lane), LDS [64][65]
// padded, packed bf16x4 stores (8B/lane).  ~288MB of weight-format traffic
// moves from ~2.5 TB/s (scalar) toward ~5-6 TB/s.  Everything else identical.
// ---------------------------------------------------------------------------

typedef __bf16 bf16;
typedef __bf16 bf16x4 __attribute__((ext_vector_type(4)));
typedef __bf16 bf16x8 __attribute__((ext_vector_type(8)));
typedef float  f32x4  __attribute__((ext_vector_type(4)));

__device__ __forceinline__ void gload16(const void* g, void* l) {
  __builtin_amdgcn_global_load_lds((const __attribute__((address_space(1))) void*)g,
                                   (__attribute__((address_space(3))) void*)l,
                                   16, 0, 0);
}

#define CBAR asm volatile("" ::: "memory")
#define WAITV(N) asm volatile("s_waitcnt vmcnt(" #N ")" ::: "memory")
#define LGKM0 asm volatile("s_waitcnt lgkmcnt(0)" ::: "memory")
#define BARR { CBAR; __builtin_amdgcn_s_barrier(); CBAR; }

// ------------------------------ RMSNorm (f32 -> bf16, linear) --------------
__global__ __launch_bounds__(256) void rmsnorm_to_bf16(
    const float* __restrict__ x, const float* __restrict__ w, bf16* __restrict__ out)
{
  const int D = 2048;
  const int row = blockIdx.x;
  const int tid = threadIdx.x;
  const float* xr = x + (size_t)row * D;
  float4 a = ((const float4*)xr)[tid * 2];
  float4 c = ((const float4*)xr)[tid * 2 + 1];
  float ss = a.x*a.x + a.y*a.y + a.z*a.z + a.w*a.w
           + c.x*c.x + c.y*c.y + c.z*c.z + c.w*c.w;
  #pragma unroll
  for (int m = 1; m < 64; m <<= 1) ss += __shfl_xor(ss, m, 64);
  __shared__ float red[4];
  if ((tid & 63) == 0) red[tid >> 6] = ss;
  __syncthreads();
  float tot = red[0] + red[1] + red[2] + red[3];
  float rms = rsqrtf(tot * (1.0f / D) + 1.1920929e-7f);
  const float* wr = w + tid * 8;
  float vals[8] = {a.x, a.y, a.z, a.w, c.x, c.y, c.z, c.w};
  bf16x8 o;
  #pragma unroll
  for (int j = 0; j < 8; ++j) o[j] = (bf16)(vals[j] * rms * wr[j]);
  *(bf16x8*)(out + (size_t)row * D + tid * 8) = o;
}

// ------ transpose + convert f32[R][C] -> bf16[C][R], 64x64 vectorized ------
// 256 thr flat (tx = tid&15, ty = tid>>4).  float4 loads, [64][65] LDS pad,
// packed bf16x4 stores.  R, C multiples of 64.
__global__ __launch_bounds__(256) void transpose_to_bf16(
    const float* __restrict__ in, bf16* __restrict__ out, int R, int C)
{
  __shared__ float tile[64][65];
  const int tid = threadIdx.x;
  const int tx = tid & 15, ty = tid >> 4;
  const int c0 = blockIdx.x * 64, r0 = blockIdx.y * 64;
  #pragma unroll
  for (int i = 0; i < 4; ++i) {
    const int r = ty + i * 16;
    const float4 v = *(const float4*)&in[(size_t)(r0 + r) * C + c0 + tx * 4];
    tile[r][tx * 4 + 0] = v.x;
    tile[r][tx * 4 + 1] = v.y;
    tile[r][tx * 4 + 2] = v.z;
    tile[r][tx * 4 + 3] = v.w;
  }
  __syncthreads();
  #pragma unroll
  for (int i = 0; i < 4; ++i) {
    const int n = ty + i * 16;              // column of input = row of output
    bf16x4 o;
    o[0] = (bf16)tile[tx * 4 + 0][n];
    o[1] = (bf16)tile[tx * 4 + 1][n];
    o[2] = (bf16)tile[tx * 4 + 2][n];
    o[3] = (bf16)tile[tx * 4 + 3][n];
    *(bf16x4*)(out + (size_t)(c0 + n) * R + r0 + tx * 4) = o;
  }
}

// ----- fused 4x (2048x2048) vectorized transpose: z selects {wq,wk,wv,wo} --
__global__ __launch_bounds__(256) void transpose4_to_bf16(
    const float* __restrict__ w0, const float* __restrict__ w1,
    const float* __restrict__ w2, const float* __restrict__ w3,
    bf16* __restrict__ o0, bf16* __restrict__ o1,
    bf16* __restrict__ o2, bf16* __restrict__ o3)
{
  const int R = 2048, C = 2048;
  __shared__ float tile[64][65];
  const int tid = threadIdx.x;
  const int tx = tid & 15, ty = tid >> 4;
  const int c0 = blockIdx.x * 64, r0 = blockIdx.y * 64;
  const int z = blockIdx.z;
  const float* in = (z == 0) ? w0 : (z == 1) ? w1 : (z == 2) ? w2 : w3;
  bf16* out = (z == 0) ? o0 : (z == 1) ? o1 : (z == 2) ? o2 : o3;
  #pragma unroll
  for (int i = 0; i < 4; ++i) {
    const int r = ty + i * 16;
    const float4 v = *(const float4*)&in[(size_t)(r0 + r) * C + c0 + tx * 4];
    tile[r][tx * 4 + 0] = v.x;
    tile[r][tx * 4 + 1] = v.y;
    tile[r][tx * 4 + 2] = v.z;
    tile[r][tx * 4 + 3] = v.w;
  }
  __syncthreads();
  #pragma unroll
  for (int i = 0; i < 4; ++i) {
    const int n = ty + i * 16;
    bf16x4 o;
    o[0] = (bf16)tile[tx * 4 + 0][n];
    o[1] = (bf16)tile[tx * 4 + 1][n];
    o[2] = (bf16)tile[tx * 4 + 2][n];
    o[3] = (bf16)tile[tx * 4 + 3][n];
    *(bf16x4*)(out + (size_t)(c0 + n) * R + r0 + tx * 4) = o;
  }
}

// --------------- V[b*L+key][h*128+dh] -> VT[(bh*128+dh)][key'] (bf16) ------
__global__ __launch_bounds__(256) void v_transpose(
    const bf16* __restrict__ v, bf16* __restrict__ vt)
{
  const int L = 2048, DM = 2048;
  __shared__ bf16 tile[32][33];
  const int tx = threadIdx.x, ty = threadIdx.y;      // 32 x 8
  const int k0 = blockIdx.x * 32;
  const int d0 = blockIdx.y * 32;
  const int bh = blockIdx.z;
  const int b = bh >> 4, h = bh & 15;
  #pragma unroll
  for (int i = 0; i < 4; ++i)
    tile[ty + i * 8][tx] = v[(size_t)(b * L + k0 + ty + i * 8) * DM + h * 128 + d0 + tx];
  __syncthreads();
  #pragma unroll
  for (int i = 0; i < 4; ++i) {
    const int d = d0 + ty + i * 8;
    const int key = k0 + tx;
    const int keysw = (key & ~63) | (((((key >> 3) & 7) ^ (d & 7)) << 3)) | (key & 7);
    vt[(size_t)(bh * 128 + d) * L + keysw] = tile[tx][ty + i * 8];
  }
}

// ------------- 256x256 4-phase GEMM, 7-unit deep prefetch (BK=64) ----------
// R11 schedule + hoisted addresses.  EPI: 2 = silu bf16
template<int EPI>
__global__ __launch_bounds__(512, 1) void gemm256(
    const bf16* __restrict__ A, const bf16* __restrict__ Bt,
    void* Cout, const float* __restrict__ resid, int M, int N, int K)
{
  __shared__ bf16 sA[2][2][128 * 64];   // 64 KB ; buf stride 32768B, rh 16384B
  __shared__ bf16 sB[2][2][128 * 64];   // 64 KB

  const int tid = threadIdx.x, lane = tid & 63, w = tid >> 6;
  const int wm = w >> 2, wn = w & 3;
  const int lo = lane & 15, hi = lane >> 4;
  const int lo7 = lo & 7;

  const int nbn = N >> 8;
  const int nwg = gridDim.x;
  int swz = blockIdx.x;
  if ((nwg & 7) == 0) { const int cpx = nwg >> 3; swz = (swz & 7) * cpx + (swz >> 3); }
  const int bm = swz / nbn, bn = swz % nbn;

  const int r0 = tid >> 3,         s0 = (tid & 7) ^ (r0 & 7);
  const int r1 = (512 + tid) >> 3, s1 = ((512 + tid) & 7) ^ (r1 & 7);
  const bf16* Ab = A  + (size_t)(bm * 256) * K;
  const bf16* Bb = Bt + (size_t)(bn * 256) * K;
  const size_t o0 = (size_t)r0 * K + s0 * 8;
  const size_t o1 = (size_t)r1 * K + s1 * 8;
  const int dst0 = (w * 64) * 8, dst1 = (512 + w * 64) * 8;
  const size_t rhK = (size_t)128 * K;

  unsigned offA[2][4], offB[2][2];
  #pragma unroll
  for (int ks = 0; ks < 2; ++ks) {
    #pragma unroll
    for (int m = 0; m < 4; ++m)
      offA[ks][m] = (unsigned)((((wm * 64 + m * 16 + lo) * 64) + (((ks * 4 + hi) ^ lo7) << 3)) * 2);
    #pragma unroll
    for (int nj = 0; nj < 2; ++nj)
      offB[ks][nj] = (unsigned)((((wn * 32 + nj * 16 + lo) * 64) + (((ks * 4 + hi) ^ lo7) << 3)) * 2);
  }

  const bf16* pA1_0 = Ab + rhK + 64 + o0;  const bf16* pA1_1 = Ab + rhK + 64 + o1;
  const bf16* pA0_0 = Ab + 128 + o0;       const bf16* pA0_1 = Ab + 128 + o1;
  const bf16* pB0_0 = Bb + 128 + o0;       const bf16* pB0_1 = Bb + 128 + o1;
  const bf16* pB1_0 = Bb + rhK + 128 + o0; const bf16* pB1_1 = Bb + rhK + 128 + o1;

  bf16x8 a0[2][4], a1[2][4], b0[2][2], b1[2][2];
  f32x4 acc[8][4] = {};
  const int NT = K >> 6;

  auto loadA = [&](bf16x8 (&d)[2][4], int b, int rh) {
    const char* base = (const char*)(&sA[0][0][0]) + b * 32768 + rh * 16384;
    #pragma unroll
    for (int ks = 0; ks < 2; ++ks)
      #pragma unroll
      for (int m = 0; m < 4; ++m)
        d[ks][m] = *(const bf16x8*)(base + offA[ks][m]);
  };
  auto loadB = [&](bf16x8 (&d)[2][2], int b, int rh) {
    const char* base = (const char*)(&sB[0][0][0]) + b * 32768 + rh * 16384;
    #pragma unroll
    for (int ks = 0; ks < 2; ++ks)
      #pragma unroll
      for (int nj = 0; nj < 2; ++nj)
        d[ks][nj] = *(const bf16x8*)(base + offB[ks][nj]);
  };
  auto mfma16 = [&](bf16x8 (&a)[2][4], bf16x8 (&bf)[2][2], int mb, int nb2) {
    __builtin_amdgcn_s_setprio(1);
    #pragma unroll
    for (int ks = 0; ks < 2; ++ks)
      #pragma unroll
      for (int m = 0; m < 4; ++m)
        #pragma unroll
        for (int nj = 0; nj < 2; ++nj)
          acc[mb + m][nb2 + nj] = __builtin_amdgcn_mfma_f32_16x16x32_bf16(
              a[ks][m], bf[ks][nj], acc[mb + m][nb2 + nj], 0, 0, 0);
    __builtin_amdgcn_s_setprio(0);
  };

  {
    gload16(Ab + o0, &sA[0][0][dst0]);        gload16(Ab + o1, &sA[0][0][dst1]);
    gload16(Bb + o0, &sB[0][0][dst0]);        gload16(Bb + o1, &sB[0][0][dst1]);
    gload16(Bb + rhK + o0, &sB[0][1][dst0]);  gload16(Bb + rhK + o1, &sB[0][1][dst1]);
    gload16(Ab + rhK + o0, &sA[0][1][dst0]);  gload16(Ab + rhK + o1, &sA[0][1][dst1]);
    gload16(Ab + 64 + o0, &sA[1][0][dst0]);   gload16(Ab + 64 + o1, &sA[1][0][dst1]);
    gload16(Bb + 64 + o0, &sB[1][0][dst0]);   gload16(Bb + 64 + o1, &sB[1][0][dst1]);
    gload16(Bb + rhK + 64 + o0, &sB[1][1][dst0]); gload16(Bb + rhK + 64 + o1, &sB[1][1][dst1]);
  }
  WAITV(6);
  BARR;

  for (int t = 0; t < NT; ++t) {
    const int buf = t & 1, nb = buf ^ 1;
    const int u = 4 * t;
    loadA(a0, buf, 0);
    loadB(b0, buf, 0);
    if (u + 7 < 4 * NT) { gload16(pA1_0, &sA[nb][1][dst0]); gload16(pA1_1, &sA[nb][1][dst1]); }
    BARR; LGKM0;
    mfma16(a0, b0, 0, 0);
    BARR;
    loadB(b1, buf, 1);
    if (u + 8 < 4 * NT) { gload16(pA0_0, &sA[buf][0][dst0]); gload16(pA0_1, &sA[buf][0][dst1]); }
    BARR; LGKM0;
    mfma16(a0, b1, 0, 2);
    BARR;
    loadA(a1, buf, 1);
    if (u + 9 < 4 * NT) { gload16(pB0_0, &sB[buf][0][dst0]); gload16(pB0_1, &sB[buf][0][dst1]); }
    BARR; LGKM0;
    mfma16(a1, b1, 4, 2);
    BARR;
    if (u + 10 < 4 * NT) { gload16(pB1_0, &sB[buf][1][dst0]); gload16(pB1_1, &sB[buf][1][dst1]); }
    mfma16(a1, b0, 4, 0);
    if (t < NT - 2) { WAITV(6); } else if (t == NT - 2) { WAITV(0); }
    BARR;
    pA1_0 += 64; pA1_1 += 64; pA0_0 += 64; pA0_1 += 64;
    pB0_0 += 64; pB0_1 += 64; pB1_0 += 64; pB1_1 += 64;
  }

  #pragma unroll
  for (int mi = 0; mi < 8; ++mi) {
    #pragma unroll
    for (int j = 0; j < 4; ++j) {
      const size_t row = (size_t)(bm * 256 + (mi >> 2) * 128 + wm * 64 + (mi & 3) * 16 + hi * 4 + j);
      #pragma unroll
      for (int ni = 0; ni < 4; ++ni) {
        const int col = bn * 256 + (ni >> 1) * 128 + wn * 32 + (ni & 1) * 16 + lo;
        const float v = acc[mi][ni][j];
        if constexpr (EPI == 2) {
          ((bf16*)Cout)[row * (size_t)N + col] = (bf16)(v / (1.0f + __expf(-v)));
        } else {
          ((bf16*)Cout)[(size_t)(col >> 11) * 8388608 + row * 2048 + (col & 2047)] = (bf16)v;
        }
      }
    }
  }
}

// ------------- 128x256 2-phase GEMM, 5-unit deep prefetch (BK=64) ----------
// R11 schedule + hoisted addresses.  EPI: 1 = f32 + resid; 3 = q/k/v slabs
template<int EPI>
__global__ __launch_bounds__(512, 1) void gemm128(
    const bf16* __restrict__ A, const bf16* __restrict__ Bt,
    void* Cout, const float* __restrict__ resid, int M, int N, int K)
{
  __shared__ bf16 sA[2][128 * 64];      // 32 KB ; buf stride 16384B
  __shared__ bf16 sB[2][2][128 * 64];   // 64 KB ; buf stride 32768B, nh 16384B

  const int tid = threadIdx.x, lane = tid & 63, w = tid >> 6;
  const int wm = w >> 2, wn = w & 3;
  const int lo = lane & 15, hi = lane >> 4;
  const int lo7 = lo & 7;

  const int nbn = N >> 8;
  const int nwg = gridDim.x;
  int swz = blockIdx.x;
  if ((nwg & 7) == 0) { const int cpx = nwg >> 3; swz = (swz & 7) * cpx + (swz >> 3); }
  const int bm = swz / nbn, bn = swz % nbn;

  const int r0 = tid >> 3,         s0 = (tid & 7) ^ (r0 & 7);
  const int r1 = (512 + tid) >> 3, s1 = ((512 + tid) & 7) ^ (r1 & 7);
  const bf16* Ab = A  + (size_t)(bm * 128) * K;
  const bf16* Bb = Bt + (size_t)(bn * 256) * K;
  const size_t o0 = (size_t)r0 * K + s0 * 8;
  const size_t o1 = (size_t)r1 * K + s1 * 8;
  const int dst0 = (w * 64) * 8, dst1 = (512 + w * 64) * 8;
  const size_t nhK = (size_t)128 * K;

  unsigned offA[2][4], offB[2][2];
  #pragma unroll
  for (int ks = 0; ks < 2; ++ks) {
    #pragma unroll
    for (int m = 0; m < 4; ++m)
      offA[ks][m] = (unsigned)((((wm * 64 + m * 16 + lo) * 64) + (((ks * 4 + hi) ^ lo7) << 3)) * 2);
    #pragma unroll
    for (int nj = 0; nj < 2; ++nj)
      offB[ks][nj] = (unsigned)((((wn * 32 + nj * 16 + lo) * 64) + (((ks * 4 + hi) ^ lo7) << 3)) * 2);
  }

  const bf16* pB1_0 = Bb + nhK + 64 + o0;  const bf16* pB1_1 = Bb + nhK + 64 + o1;
  const bf16* pA_0  = Ab + 128 + o0;       const bf16* pA_1  = Ab + 128 + o1;
  const bf16* pB0_0 = Bb + 128 + o0;       const bf16* pB0_1 = Bb + 128 + o1;

  bf16x8 afA[2][4], b0[2][2], b1[2][2];
  f32x4 acc[4][4] = {};
  const int NT = K >> 6;

  auto loadA = [&](int b) {
    const char* base = (const char*)(&sA[0][0]) + b * 16384;
    #pragma unroll
    for (int ks = 0; ks < 2; ++ks)
      #pragma unroll
      for (int m = 0; m < 4; ++m)
        afA[ks][m] = *(const bf16x8*)(base + offA[ks][m]);
  };
  auto loadB = [&](bf16x8 (&d)[2][2], int b, int nh) {
    const char* base = (const char*)(&sB[0][0][0]) + b * 32768 + nh * 16384;
    #pragma unroll
    for (int ks = 0; ks < 2; ++ks)
      #pragma unroll
      for (int nj = 0; nj < 2; ++nj)
        d[ks][nj] = *(const bf16x8*)(base + offB[ks][nj]);
  };
  auto mfma16 = [&](bf16x8 (&bf)[2][2], int nb2) {
    __builtin_amdgcn_s_setprio(1);
    #pragma unroll
    for (int ks = 0; ks < 2; ++ks)
      #pragma unroll
      for (int m = 0; m < 4; ++m)
        #pragma unroll
        for (int nj = 0; nj < 2; ++nj)
          acc[m][nb2 + nj] = __builtin_amdgcn_mfma_f32_16x16x32_bf16(
              afA[ks][m], bf[ks][nj], acc[m][nb2 + nj], 0, 0, 0);
    __builtin_amdgcn_s_setprio(0);
  };

  {
    gload16(Ab + o0, &sA[0][dst0]);           gload16(Ab + o1, &sA[0][dst1]);
    gload16(Bb + o0, &sB[0][0][dst0]);        gload16(Bb + o1, &sB[0][0][dst1]);
    gload16(Bb + nhK + o0, &sB[0][1][dst0]);  gload16(Bb + nhK + o1, &sB[0][1][dst1]);
    gload16(Ab + 64 + o0, &sA[1][dst0]);      gload16(Ab + 64 + o1, &sA[1][dst1]);
    gload16(Bb + 64 + o0, &sB[1][0][dst0]);   gload16(Bb + 64 + o1, &sB[1][0][dst1]);
  }
  WAITV(4);
  BARR;

  for (int t = 0; t < NT; ++t) {
    const int buf = t & 1, nb = buf ^ 1;
    const int u = 3 * t;
    loadA(buf);
    loadB(b0, buf, 0);
    if (u + 5 < 3 * NT) { gload16(pB1_0, &sB[nb][1][dst0]); gload16(pB1_1, &sB[nb][1][dst1]); }
    BARR; LGKM0;
    mfma16(b0, 0);
    BARR;
    loadB(b1, buf, 1);
    if (u + 6 < 3 * NT) { gload16(pA_0, &sA[buf][dst0]); gload16(pA_1, &sA[buf][dst1]); }
    if (u + 7 < 3 * NT) { gload16(pB0_0, &sB[buf][0][dst0]); gload16(pB0_1, &sB[buf][0][dst1]); }
    BARR; LGKM0;
    mfma16(b1, 2);
    if (t < NT - 2) { WAITV(4); } else if (t == NT - 2) { WAITV(0); }
    BARR;
    pB1_0 += 64; pB1_1 += 64; pA_0 += 64; pA_1 += 64; pB0_0 += 64; pB0_1 += 64;
  }

  #pragma unroll
  for (int mi = 0; mi < 4; ++mi) {
    #pragma unroll
    for (int j = 0; j < 4; ++j) {
      const size_t row = (size_t)(bm * 128 + wm * 64 + mi * 16 + hi * 4 + j);
      #pragma unroll
      for (int ni = 0; ni < 4; ++ni) {
        const int col = bn * 256 + (ni >> 1) * 128 + wn * 32 + (ni & 1) * 16 + lo;
        const float v = acc[mi][ni][j];
        if constexpr (EPI == 1) {
          const size_t ro = row * (size_t)N;
          ((float*)Cout)[ro + col] = v + resid[ro + col];
        } else {
          ((bf16*)Cout)[(size_t)(col >> 11) * 8388608 + row * 2048 + (col & 2047)] = (bf16)v;
        }
      }
    }
  }
}

// ------------------- RoPE: q in-place; k -> kswz with granule swizzle ------
__global__ __launch_bounds__(256) void rope_qk(
    bf16* q, const bf16* __restrict__ k, bf16* __restrict__ kswz,
    const float* __restrict__ cs, const float* __restrict__ sn)
{
  const int L = 2048, DM = 2048;
  const int idx = blockIdx.x * 256 + threadIdx.x;
  const int m = idx >> 7;
  const int rem = idx & 127;
  const int h = rem >> 3, t8 = rem & 7;
  const int pos = m & (L - 1);
  const int d0 = t8 * 8;
  const float* cb = cs + (size_t)pos * 128 + d0;
  const float* sb = sn + (size_t)pos * 128 + d0;
  float4 c1a = *(const float4*)(cb);      float4 c1b = *(const float4*)(cb + 4);
  float4 c2a = *(const float4*)(cb + 64); float4 c2b = *(const float4*)(cb + 68);
  float4 s1a = *(const float4*)(sb);      float4 s1b = *(const float4*)(sb + 4);
  float4 s2a = *(const float4*)(sb + 64); float4 s2b = *(const float4*)(sb + 68);
  float c1[8] = {c1a.x,c1a.y,c1a.z,c1a.w,c1b.x,c1b.y,c1b.z,c1b.w};
  float c2[8] = {c2a.x,c2a.y,c2a.z,c2a.w,c2b.x,c2b.y,c2b.z,c2b.w};
  float s1[8] = {s1a.x,s1a.y,s1a.z,s1a.w,s1b.x,s1b.y,s1b.z,s1b.w};
  float s2[8] = {s2a.x,s2a.y,s2a.z,s2a.w,s2b.x,s2b.y,s2b.z,s2b.w};
  const size_t base = (size_t)m * DM + h * 128 + d0;

  {
    bf16x8 x1 = *(bf16x8*)(q + base);
    bf16x8 x2 = *(bf16x8*)(q + base + 64);
    bf16x8 o1, o2;
    #pragma unroll
    for (int j = 0; j < 8; ++j) {
      const float a = (float)x1[j], b = (float)x2[j];
      o1[j] = (bf16)(a * c1[j] - b * s1[j]);
      o2[j] = (bf16)(b * c2[j] + a * s2[j]);
    }
    *(bf16x8*)(q + base) = o1;
    *(bf16x8*)(q + base + 64) = o2;
  }
  {
    bf16x8 x1 = *(const bf16x8*)(k + base);
    bf16x8 x2 = *(const bf16x8*)(k + base + 64);
    bf16x8 o1, o2;
    #pragma unroll
    for (int j = 0; j < 8; ++j) {
      const float a = (float)x1[j], b = (float)x2[j];
      o1[j] = (bf16)(a * c1[j] - b * s1[j]);
      o2[j] = (bf16)(b * c2[j] + a * s2[j]);
    }
    const int s = pos & 15;
    const int p1 = t8 ^ s;
    const int p2 = (8 + t8) ^ s;
    bf16* kr = kswz + (size_t)m * DM + h * 128;
    *(bf16x8*)(kr + p1 * 8) = o1;
    *(bf16x8*)(kr + p2 * 8) = o2;
  }
}

// ------------------------------ Flash attention (R13, verified) ------------
__global__ __launch_bounds__(256, 2) void attn_fwd(
    const bf16* __restrict__ Q, const bf16* __restrict__ Kswz,
    const bf16* __restrict__ VT, const int* __restrict__ mask,
    bf16* __restrict__ O)
{
  const int L = 2048, DM = 2048;
  __shared__ bf16 Kt[2][64 * 128];
  __shared__ bf16 Vt[2][128 * 64];
  __shared__ bf16 Plds[4][16 * 64];

  const int tid = threadIdx.x, lane = tid & 63, w = tid >> 6;
  const int lo = lane & 15, hi = lane >> 4;
  const int s7 = lo & 7;
  const int n = blockIdx.x;
  const int xcd = n & 7, slot = n >> 3;
  const int bh = xcd + 8 * (slot >> 4);
  const int xp = slot & 15;
  const int b = bh >> 4, h = bh & 15;
  const float scale = 0.08838834764831845f;
  const float NEG_INF = -__builtin_inff();

  const bf16* vsrc[4];
  const bf16* ksrc[4];
  #pragma unroll
  for (int i = 0; i < 4; ++i) {
    const int gv = i * 256 + tid;
    vsrc[i] = VT + (size_t)(bh * 128 + (gv >> 3)) * L + (gv & 7) * 8;
    const int gk = i * 256 + tid;
    ksrc[i] = Kswz + (size_t)(b * L + (gk >> 4)) * DM + h * 128 + (gk & 15) * 8;
  }

  for (int pass = 0; pass < 2; ++pass) {
    const int tile = pass ? xp : (31 - xp);
    const int qrow = tile * 64 + w * 16;

    bf16x8 qf[4];
    {
      const bf16* qb = Q + (size_t)(b * L + qrow + lo) * DM + h * 128;
      #pragma unroll
      for (int ds = 0; ds < 4; ++ds) qf[ds] = *(const bf16x8*)(qb + ds * 32 + hi * 8);
    }

    float mrow[4] = {NEG_INF, NEG_INF, NEG_INF, NEG_INF};
    float lrow[4] = {0.f, 0.f, 0.f, 0.f};
    f32x4 oacc[8] = {};

    #pragma unroll
    for (int i = 0; i < 4; ++i) {
      gload16(ksrc[i], &Kt[0][(i * 256 + w * 64) * 8]);
      gload16(vsrc[i], &Vt[0][(i * 256 + w * 64) * 8]);
    }
    __syncthreads();

    const int nkt = tile + 1;
    for (int kt = 0; kt < nkt; ++kt) {
      const int buf = kt & 1;
      if (kt + 1 < nkt) {
        #pragma unroll
        for (int i = 0; i < 4; ++i) {
          gload16(ksrc[i] + (size_t)(kt + 1) * 64 * DM, &Kt[buf ^ 1][(i * 256 + w * 64) * 8]);
          gload16(vsrc[i] + (kt + 1) * 64,              &Vt[buf ^ 1][(i * 256 + w * 64) * 8]);
        }
      }

      int mk[4];
      #pragma unroll
      for (int kb = 0; kb < 4; ++kb) mk[kb] = mask[b * L + kt * 64 + kb * 16 + lo];

      f32x4 S[4];
      __builtin_amdgcn_s_setprio(1);
      #pragma unroll
      for (int kb = 0; kb < 4; ++kb) {
        f32x4 s = {};
        #pragma unroll
        for (int ds = 0; ds < 4; ++ds) {
          const bf16x8 kf = *(const bf16x8*)&Kt[buf][(kb * 16 + lo) * 128 + (((ds * 4 + hi) ^ lo) * 8)];
          s = __builtin_amdgcn_mfma_f32_16x16x32_bf16(qf[ds], kf, s, 0, 0, 0);
        }
        S[kb] = s;
      }
      __builtin_amdgcn_s_setprio(0);

      #pragma unroll
      for (int kb = 0; kb < 4; ++kb) {
        const int kidx = kt * 64 + kb * 16 + lo;
        #pragma unroll
        for (int j = 0; j < 4; ++j) {
          const float sv = S[kb][j] * scale;
          S[kb][j] = (mk[kb] != 0 && kidx <= qrow + hi * 4 + j) ? sv : NEG_INF;
        }
      }

      float p[4][4];
      #pragma unroll
      for (int j = 0; j < 4; ++j) {
        float tm = fmaxf(fmaxf(S[0][j], S[1][j]), fmaxf(S[2][j], S[3][j]));
        tm = fmaxf(tm, __shfl_xor(tm, 1, 64));
        tm = fmaxf(tm, __shfl_xor(tm, 2, 64));
        tm = fmaxf(tm, __shfl_xor(tm, 4, 64));
        tm = fmaxf(tm, __shfl_xor(tm, 8, 64));
        const float mn = fmaxf(mrow[j], tm);
        const float mn2 = (mn == NEG_INF) ? 0.f : mn;
        const float alpha = __expf(mrow[j] - mn2);
        float ps = 0.f;
        #pragma unroll
        for (int kb = 0; kb < 4; ++kb) { p[kb][j] = __expf(S[kb][j] - mn2); ps += p[kb][j]; }
        ps += __shfl_xor(ps, 1, 64);
        ps += __shfl_xor(ps, 2, 64);
        ps += __shfl_xor(ps, 4, 64);
        ps += __shfl_xor(ps, 8, 64);
        lrow[j] = lrow[j] * alpha + ps;
        mrow[j] = mn;
        #pragma unroll
        for (int n2 = 0; n2 < 8; ++n2) oacc[n2][j] *= alpha;
      }

      #pragma unroll
      for (int kb = 0; kb < 4; ++kb)
        #pragma unroll
        for (int j = 0; j < 4; ++j) {
          const int row = hi * 4 + j;
          Plds[w][row * 64 + ((((kb * 2 + (lo >> 3)) ^ (row & 7))) << 3) + (lo & 7)] = (bf16)p[kb][j];
        }

      __builtin_amdgcn_s_setprio(1);
      #pragma unroll
      for (int ks = 0; ks < 2; ++ks) {
        const bf16x8 pa = *(const bf16x8*)&Plds[w][lo * 64 + (((ks * 4 + hi) ^ s7) << 3)];
        #pragma unroll
        for (int n2 = 0; n2 < 8; ++n2) {
          const int r = n2 * 16 + lo;
          const bf16x8 vf = *(const bf16x8*)&Vt[buf][r * 64 + (((ks * 4 + hi) ^ s7) << 3)];
          oacc[n2] = __builtin_amdgcn_mfma_f32_16x16x32_bf16(pa, vf, oacc[n2], 0, 0, 0);
        }
      }
      __builtin_amdgcn_s_setprio(0);

      __syncthreads();
    }

    float inv[4];
    #pragma unroll
    for (int j = 0; j < 4; ++j) inv[j] = (lrow[j] > 0.f) ? 1.f / lrow[j] : 0.f;
    bf16* ob = O + (size_t)(b * L + qrow) * DM + h * 128;
    #pragma unroll
    for (int n2 = 0; n2 < 8; ++n2)
      #pragma unroll
      for (int j = 0; j < 4; ++j)
        ob[(size_t)(hi * 4 + j) * DM + n2 * 16 + lo] = (bf16)(oacc[n2][j] * inv[j]);
  }
}

// ---------------------------------------------------------------------------
extern "C" void kernel_launch(void* const* d_in, const int* in_sizes, int n_in,
                              void* d_out, int out_size, void* d_ws, size_t ws_size,
                              hipStream_t stream)
{
  (void)in_sizes; (void)n_in; (void)out_size; (void)ws_size;
  const float* x        = (const float*)d_in[0];
  const float* rope_cos = (const float*)d_in[1];
  const float* rope_sin = (const float*)d_in[2];
  const int*   mask     = (const int*)d_in[3];
  const float* w_norm1  = (const float*)d_in[4];
  const float* w_norm2  = (const float*)d_in[5];
  const float* wq       = (const float*)d_in[6];
  const float* wk       = (const float*)d_in[7];
  const float* wv       = (const float*)d_in[8];
  const float* wo       = (const float*)d_in[9];
  const float* w_ff1    = (const float*)d_in[10];
  const float* w_ff2    = (const float*)d_in[11];
  float* out = (float*)d_out;

  const int M = 4096, D = 2048, FFD = 8192;
  char* ws = (char*)d_ws;
  const size_t WSLAB = 8388608ull;    // 2048*2048*2 B
  const size_t XNB   = 16777216ull;   // 4096*2048*2 B
  bf16* wqt  = (bf16*)(ws);           // wqt|wkt|wvt contiguous = [6144][2048]
  bf16* wkt  = (bf16*)(ws + WSLAB);
  bf16* wvt  = (bf16*)(ws + 2 * WSLAB);
  bf16* wot  = (bf16*)(ws + 3 * WSLAB);
  char* pool = ws + 4 * WSLAB;
  bf16* xn   = (bf16*)(pool);
  bf16* qb   = (bf16*)(pool + XNB);
  bf16* kb   = (bf16*)(pool + 2 * XNB);
  bf16* vb   = (bf16*)(pool + 3 * XNB);
  bf16* ao   = (bf16*)(pool + 4 * XNB);
  bf16* vt   = (bf16*)(pool);               // reuses xn after QKV GEMM
  bf16* kswz = (bf16*)(pool + 3 * XNB);     // reuses vb after v_transpose
  bf16* ff1t = (bf16*)(ws);                 // reuses wq_t..wo_t after WO GEMM
  bf16* hmid = (bf16*)(pool);               // reuses vt|qb|kb after attention
  bf16* ff2t = (bf16*)(ws);                 // reuses ff1_t after FF1
  bf16* xn2  = (bf16*)(pool + 4 * XNB);     // reuses ao after WO GEMM

  const dim3 tb(32, 8);

  rmsnorm_to_bf16<<<M, 256, 0, stream>>>(x, w_norm1, xn);
  transpose4_to_bf16<<<dim3(D / 64, D / 64, 4), 256, 0, stream>>>(
      wq, wk, wv, wo, wqt, wkt, wvt, wot);

  // fused QKV on gemm128: 768 blocks = 3 exact rounds; Bt = [6144][2048]
  gemm128<3><<<(M / 128) * (6144 / 256), 512, 0, stream>>>(xn, wqt, qb, nullptr, M, 6144, D);

  // xn dead after QKV GEMM; vt overwrites it
  v_transpose<<<dim3(2048 / 32, 128 / 32, 32), tb, 0, stream>>>(vb, vt);

  // vb dead after v_transpose; kswz overwrites it
  rope_qk<<<2048, 256, 0, stream>>>(qb, kb, kswz, rope_cos, rope_sin);

  attn_fwd<<<512, 256, 0, stream>>>(qb, kswz, vt, mask, ao);

  // WO on the 128x256 pipeline (256 blocks = 1 full round)
  gemm128<1><<<(M / 128) * (D / 256), 512, 0, stream>>>(ao, wot, out, x, M, D, D);

  rmsnorm_to_bf16<<<M, 256, 0, stream>>>(out, w_norm2, xn2);

  transpose_to_bf16<<<dim3(FFD / 64, D / 64), 256, 0, stream>>>(w_ff1, ff1t, D, FFD);
  gemm256<2><<<(M / 256) * (FFD / 256), 512, 0, stream>>>(xn2, ff1t, hmid, nullptr, M, FFD, D);

  transpose_to_bf16<<<dim3(D / 64, FFD / 64), 256, 0, stream>>>(w_ff2, ff2t, FFD, D);
  gemm128<1><<<(M / 128) * (D / 256), 512, 0, stream>>>(hmid, ff2t, out, out, M, D, FFD);
}